// Round 3
// baseline (2623.215 us; speedup 1.0000x reference)
//
#include <hip/hip_runtime.h>

#define DEV static __device__ __forceinline__

constexpr int BATCH = 256;

DEV float leakyf(float x){ return x > 0.f ? x : 0.2f * x; }

// 16B vector load with only 4B alignment guarantee (unaligned float4)
struct __attribute__((packed, aligned(4))) f4u { float x, y, z, w; };

// ---------------- weight transpose: w[OC][RED] -> wT[RED][OC] ----------------
__global__ __launch_bounds__(256) void kwT(const float* __restrict__ w,
                                           float* __restrict__ wt, int OC, int RED){
  int i = blockIdx.x * 256 + threadIdx.x;
  if (i >= OC * RED) return;
  int oc = i / RED, r = i % RED;
  wt[r * OC + oc] = w[i];
}

// ---------------- register-blocked direct conv ------------------------------
// Each thread: 4 consecutive ow pixels x OCG output channels.
// Block: GPR pixel-groups x RPB rows = GPR*RPB threads. Weights (OCG slice)
// staged in LDS, read as uniform-address ds_read_b128 (broadcast).
// VEC: stride-1 path, one unaligned 8-float load per (ic,kh), reused over kw.
// ACT: 0 = bias+leaky, 1 = bias+BN(eval)+relu
template<int IC,int OC,int OCG,int K,int S,int P,int IH,int IW,int OH,int OW,
         int ACT,int GPR,int RPB,bool VEC>
__global__ __launch_bounds__(256) void convT_k(
    const float* __restrict__ in, const float* __restrict__ wT,
    const float* __restrict__ bias,
    const float* __restrict__ bng, const float* __restrict__ bnb,
    const float* __restrict__ bnm, const float* __restrict__ bnv,
    float* __restrict__ out){
  constexpr int RED = IC * K * K;
  __shared__ float wlds[RED * OCG];

  const int tid = threadIdx.x;
  const int ocb = blockIdx.y * OCG;
  // stage weight slice: wT[k][ocb..ocb+OCG)
  for (int i = tid; i < RED * OCG; i += GPR * RPB){
    int k = i / OCG, j = i % OCG;
    wlds[i] = wT[(size_t)k * OC + ocb + j];
  }
  __syncthreads();

  const int g = tid % GPR;          // pixel group in row
  const int r = tid / GPR;          // row within block
  const int row = blockIdx.x * RPB + r;
  const bool trow = (row < BATCH * OH);
  const int n = row / OH, oh = row % OH;
  const int ow0 = 4 * g;

  float acc[4][OCG];
  #pragma unroll
  for (int e = 0; e < 4; ++e)
    #pragma unroll
    for (int j = 0; j < OCG; ++j) acc[e][j] = 0.f;

  for (int ic = 0; ic < IC; ++ic){
    const float* chan = in + ((size_t)n * IC + ic) * IH * IW;
    #pragma unroll
    for (int kh = 0; kh < K; ++kh){
      const int ih = oh * S - P + kh;
      const bool rv = trow && (ih >= 0) && (ih < IH);
      const float* rowp = chan + (long)ih * IW;

      if (VEC){
        // stride-1: load 8 floats covering kw+e in [0, K+2] (K==3 -> 6 used)
        float vv[8];
        if (rv){
          f4u lo = *reinterpret_cast<const f4u*>(rowp + ow0 - P);
          f4u hi = *reinterpret_cast<const f4u*>(rowp + ow0 - P + 4);
          vv[0]=lo.x; vv[1]=lo.y; vv[2]=lo.z; vv[3]=lo.w;
          vv[4]=hi.x; vv[5]=hi.y; vv[6]=hi.z; vv[7]=hi.w;
        } else {
          #pragma unroll
          for (int m = 0; m < 8; ++m) vv[m] = 0.f;
        }
        #pragma unroll
        for (int m = 0; m < K + 3; ++m){
          int iw = ow0 - P + m;
          if (iw < 0 || iw >= IW) vv[m] = 0.f;
        }
        #pragma unroll
        for (int kw = 0; kw < K; ++kw){
          const float* wr = &wlds[((ic * K + kh) * K + kw) * OCG];
          float w[OCG];
          #pragma unroll
          for (int q = 0; q < OCG / 4; ++q){
            float4 wq = *reinterpret_cast<const float4*>(wr + 4 * q);
            w[4*q+0]=wq.x; w[4*q+1]=wq.y; w[4*q+2]=wq.z; w[4*q+3]=wq.w;
          }
          #pragma unroll
          for (int e = 0; e < 4; ++e){
            float v = vv[kw + e];
            #pragma unroll
            for (int j = 0; j < OCG; ++j) acc[e][j] += v * w[j];
          }
        }
      } else {
        #pragma unroll
        for (int kw = 0; kw < K; ++kw){
          float ve[4];
          #pragma unroll
          for (int e = 0; e < 4; ++e){
            int iw = (ow0 + e) * S - P + kw;
            ve[e] = 0.f;
            if (rv && iw >= 0 && iw < IW) ve[e] = rowp[iw];
          }
          const float* wr = &wlds[((ic * K + kh) * K + kw) * OCG];
          float w[OCG];
          #pragma unroll
          for (int q = 0; q < OCG / 4; ++q){
            float4 wq = *reinterpret_cast<const float4*>(wr + 4 * q);
            w[4*q+0]=wq.x; w[4*q+1]=wq.y; w[4*q+2]=wq.z; w[4*q+3]=wq.w;
          }
          #pragma unroll
          for (int e = 0; e < 4; ++e){
            #pragma unroll
            for (int j = 0; j < OCG; ++j) acc[e][j] += ve[e] * w[j];
          }
        }
      }
    }
  }

  if (!trow) return;
  #pragma unroll
  for (int j = 0; j < OCG; ++j){
    const int oc = ocb + j;
    float b = bias[oc], sc = 1.f, mm = 0.f, bb = 0.f;
    if (ACT == 1){
      sc = bng[oc] * __frsqrt_rn(bnv[oc] + 1e-5f);
      mm = bnm[oc]; bb = bnb[oc];
    }
    float* op = out + ((size_t)(n * OC + oc) * OH + oh) * OW;
    #pragma unroll
    for (int e = 0; e < 4; ++e){
      const int ow = ow0 + e;
      if (ow >= OW) continue;
      float val = acc[e][j] + b;
      if (ACT == 1) val = fmaxf((val - mm) * sc + bb, 0.f);
      else          val = leakyf(val);
      op[ow] = val;
    }
  }
}

// ---------------- 2x2 stride-1 maxpool ----------------
template<int C,int IH,int IW>
__global__ __launch_bounds__(256) void pool_k(const float* __restrict__ in,
                                              float* __restrict__ out){
  constexpr int OH = IH - 1, OW = IW - 1;
  int idx = blockIdx.x * 256 + threadIdx.x;
  if (idx >= BATCH * C * OH * OW) return;
  int ow = idx % OW; int t = idx / OW;
  int oh = t % OH;   t /= OH;          // t = n*C + c
  const float* p = in + ((size_t)t * IH + oh) * IW + ow;
  out[idx] = fmaxf(fmaxf(p[0], p[1]), fmaxf(p[IW], p[IW + 1]));
}

// ---------------- scout gate: spatial mean -> logits -> softmax -> top2 -----
__global__ __launch_bounds__(256) void gate_k(const float* __restrict__ s2,
                                              const float* __restrict__ cw,
                                              const float* __restrict__ cb,
                                              float* __restrict__ comb){
  int n = blockIdx.x;
  int tid = threadIdx.x;
  int c = tid >> 3;     // 0..31
  int sub = tid & 7;    // 0..7
  const float* p = s2 + ((size_t)n * 32 + c) * 784;
  float s = 0.f;
  for (int i = sub * 98; i < sub * 98 + 98; ++i) s += p[i];
  __shared__ float red[32][8];
  red[c][sub] = s;
  __syncthreads();
  if (tid < 32){
    float tot = 0.f;
    #pragma unroll
    for (int k = 0; k < 8; ++k) tot += red[tid][k];
    red[tid][0] = tot / 784.f;
  }
  __syncthreads();
  if (tid == 0){
    float lg[3];
    for (int e = 0; e < 3; ++e){
      float a = cb[e];
      for (int c2 = 0; c2 < 32; ++c2) a += red[c2][0] * cw[e * 32 + c2];
      lg[e] = a;
    }
    float m = fmaxf(lg[0], fmaxf(lg[1], lg[2]));
    float ex[3], sum = 0.f;
    for (int e = 0; e < 3; ++e){ ex[e] = expf(lg[e] - m); sum += ex[e]; }
    float pr[3];
    for (int e = 0; e < 3; ++e) pr[e] = ex[e] / sum;
    int i1 = 0;
    if (pr[1] > pr[0]) i1 = 1;
    if (pr[2] > pr[i1]) i1 = 2;
    int i2 = -1;
    for (int e = 0; e < 3; ++e){
      if (e == i1) continue;
      if (i2 < 0 || pr[e] > pr[i2]) i2 = e;
    }
    float s12 = pr[i1] + pr[i2] + 1e-6f;
    float cmb[3] = {0.f, 0.f, 0.f};
    cmb[i1] = pr[i1] / s12;
    cmb[i2] = pr[i2] / s12;
    comb[n * 3 + 0] = cmb[0];
    comb[n * 3 + 1] = cmb[1];
    comb[n * 3 + 2] = cmb[2];
  }
}

// ------ fused maxpool2s1(27->26) + adaptive avg pool(26->3), write flat -----
__global__ __launch_bounds__(256) void papool_k(const float* __restrict__ in,
                                                float* __restrict__ flat){
  int idx = blockIdx.x * 256 + threadIdx.x;
  if (idx >= BATCH * 128 * 9) return;
  int j = idx % 3; int t = idx / 3;
  int i = t % 3;   t /= 3;
  int c = t % 128; int n = t / 128;
  int hs = (i * 26) / 3, he = ((i + 1) * 26 + 2) / 3;
  int ws = (j * 26) / 3, we = ((j + 1) * 26 + 2) / 3;
  const float* p = in + ((size_t)n * 128 + c) * 729;
  float s = 0.f;
  for (int r = hs; r < he; ++r){
    const float* r0 = p + r * 27;
    const float* r1 = r0 + 27;
    for (int cc = ws; cc < we; ++cc){
      float m = fmaxf(fmaxf(r0[cc], r0[cc + 1]), fmaxf(r1[cc], r1[cc + 1]));
      s += m;
    }
  }
  flat[(size_t)n * 1152 + c * 9 + i * 3 + j] = s / (float)((he - hs) * (we - ws));
}

// ---------------- tiled GEMM: out[M,N] = A[M,K] * W[N,K]^T + bias -----------
template<int ACT>
__global__ __launch_bounds__(256) void gemm_k(const float* __restrict__ A,
                                              const float* __restrict__ W,
                                              const float* __restrict__ bias,
                                              float* __restrict__ out,
                                              int M, int N, int K, long strideA){
  int e = blockIdx.z;
  A += (size_t)e * strideA;
  W += (size_t)e * N * K;
  bias += e * N;
  out += (size_t)e * M * N;

  __shared__ float As[16][68];
  __shared__ float Bs[16][68];
  int tid = threadIdx.x;
  int m0 = blockIdx.y * 64, n0 = blockIdx.x * 64;
  int lr = tid >> 2;
  int lk = (tid & 3) * 4;
  int tx = tid & 15, ty = tid >> 4;
  float acc[4][4] = {};

  for (int k0 = 0; k0 < K; k0 += 16){
    float4 av = *(const float4*)&A[(size_t)(m0 + lr) * K + k0 + lk];
    float4 bv = *(const float4*)&W[(size_t)(n0 + lr) * K + k0 + lk];
    As[lk + 0][lr] = av.x; As[lk + 1][lr] = av.y;
    As[lk + 2][lr] = av.z; As[lk + 3][lr] = av.w;
    Bs[lk + 0][lr] = bv.x; Bs[lk + 1][lr] = bv.y;
    Bs[lk + 2][lr] = bv.z; Bs[lk + 3][lr] = bv.w;
    __syncthreads();
    #pragma unroll
    for (int k = 0; k < 16; ++k){
      float a[4], b[4];
      #pragma unroll
      for (int i = 0; i < 4; ++i) a[i] = As[k][ty * 4 + i];
      #pragma unroll
      for (int j = 0; j < 4; ++j) b[j] = Bs[k][tx * 4 + j];
      #pragma unroll
      for (int i = 0; i < 4; ++i)
        #pragma unroll
        for (int j = 0; j < 4; ++j) acc[i][j] += a[i] * b[j];
    }
    __syncthreads();
  }

  #pragma unroll
  for (int i = 0; i < 4; ++i){
    int m = m0 + ty * 4 + i;
    #pragma unroll
    for (int j = 0; j < 4; ++j){
      int nn = n0 + tx * 4 + j;
      float v = acc[i][j] + bias[nn];
      if (ACT == 1) v = leakyf(v);
      out[(size_t)m * N + nn] = v;
    }
  }
}

// ---------------- final gated combine ----------------
__global__ __launch_bounds__(256) void comb_k(const float* __restrict__ h3,
                                              const float* __restrict__ comb,
                                              float* __restrict__ out){
  int idx = blockIdx.x * 256 + threadIdx.x;
  if (idx >= BATCH * 512) return;
  int o = idx % 512, b = idx / 512;
  float s = 0.f;
  #pragma unroll
  for (int e = 0; e < 3; ++e)
    s += comb[b * 3 + e] * h3[((size_t)e * BATCH + b) * 512 + o];
  out[idx] = s;
}

// ============================================================================
extern "C" void kernel_launch(void* const* d_in, const int* in_sizes, int n_in,
                              void* d_out, int out_size, void* d_ws, size_t ws_size,
                              hipStream_t stream){
  const float* x    = (const float*)d_in[0];
  const float* tw1  = (const float*)d_in[1];  const float* tb1 = (const float*)d_in[2];
  const float* tw2  = (const float*)d_in[3];  const float* tb2 = (const float*)d_in[4];
  const float* tw3  = (const float*)d_in[5];  const float* tb3 = (const float*)d_in[6];
  const float* tw4  = (const float*)d_in[7];  const float* tb4 = (const float*)d_in[8];
  const float* sw1  = (const float*)d_in[9];  const float* sb1 = (const float*)d_in[10];
  const float* bn1g = (const float*)d_in[11]; const float* bn1b = (const float*)d_in[12];
  const float* bn1m = (const float*)d_in[13]; const float* bn1v = (const float*)d_in[14];
  const float* sw2  = (const float*)d_in[15]; const float* sb2 = (const float*)d_in[16];
  const float* bn2g = (const float*)d_in[17]; const float* bn2b = (const float*)d_in[18];
  const float* bn2m = (const float*)d_in[19]; const float* bn2v = (const float*)d_in[20];
  const float* cw   = (const float*)d_in[21]; const float* cb  = (const float*)d_in[22];
  const float* ew1  = (const float*)d_in[23]; const float* eb1 = (const float*)d_in[24];
  const float* ew2  = (const float*)d_in[25]; const float* eb2 = (const float*)d_in[26];
  const float* ew3  = (const float*)d_in[27]; const float* eb3 = (const float*)d_in[28];
  float* out = (float*)d_out;

  // ---- workspace layout (floats), ~154.5 MB total (same as passing round) --
  float* ws = (float*)d_ws;
  size_t off = 0;
  float* comb  = ws + off; off += 768;
  float* tw1T  = ws + off; off += 16 * 27;
  float* tw2T  = ws + off; off += 32 * 400;
  float* tw3T  = ws + off; off += 64 * 288;
  float* tw4T  = ws + off; off += 128 * 576;
  float* sw1T  = ws + off; off += 16 * 147;
  float* sw2T  = ws + off; off += 32 * 144;
  float* flat  = ws + off; off += (size_t)BATCH * 1152;
  float* h1    = ws + off; off += (size_t)BATCH * 3 * 1024;
  float* h2    = ws + off; off += (size_t)BATCH * 3 * 512;
  float* h3    = ws + off; off += (size_t)BATCH * 3 * 512;
  off += 16;                                                    // guard pad
  float* bufA  = ws + off; off += (size_t)BATCH * 16 * 56 * 56; // 12,845,056
  off += 16;                                                    // guard pad
  float* bufB  = ws + off; off += (size_t)BATCH * 128 * 27 * 27;// 23,887,872
  off += 16;                                                    // guard pad
  (void)ws_size; (void)in_sizes; (void)n_in; (void)out_size;

  dim3 blk(256);

  // ---- transpose all conv weights to [red][OC] ----
  kwT<<<dim3(( 16*27 +255)/256), blk, 0, stream>>>(tw1, tw1T, 16, 27);
  kwT<<<dim3(( 32*400+255)/256), blk, 0, stream>>>(tw2, tw2T, 32, 400);
  kwT<<<dim3(( 64*288+255)/256), blk, 0, stream>>>(tw3, tw3T, 64, 288);
  kwT<<<dim3((128*576+255)/256), blk, 0, stream>>>(tw4, tw4T, 128, 576);
  kwT<<<dim3(( 16*147+255)/256), blk, 0, stream>>>(sw1, sw1T, 16, 147);
  kwT<<<dim3(( 32*144+255)/256), blk, 0, stream>>>(sw2, sw2T, 32, 144);

  // ---- scout router ----
  // scout1: 3->16 k7 s4 p3, 224->56. rows=256*56=14336, GPR=14, RPB=18 -> 252thr
  convT_k<3,16,16,7,4,3,224,224,56,56,1,14,18,false>
      <<<dim3(797,1), 252, 0, stream>>>(x, sw1T, sb1, bn1g, bn1b, bn1m, bn1v, bufA);
  // scout2: 16->32 k3 s2 p1, 56->28. rows=7168, GPR=7, RPB=36
  convT_k<16,32,16,3,2,1,56,56,28,28,1,7,36,false>
      <<<dim3(200,2), 252, 0, stream>>>(bufA, sw2T, sb2, bn2g, bn2b, bn2m, bn2v, bufB);
  gate_k<<<dim3(256), blk, 0, stream>>>(bufB, cw, cb, comb);

  // ---- trunk ----
  // conv1: 3->16 k3 s4 p1, 224->56
  convT_k<3,16,16,3,4,1,224,224,56,56,0,14,18,false>
      <<<dim3(797,1), 252, 0, stream>>>(x, tw1T, tb1, nullptr,nullptr,nullptr,nullptr, bufA);
  pool_k<16,56,56><<<dim3(48400), blk, 0, stream>>>(bufA, bufB);   // ->[B,16,55,55]
  // conv2: 16->32 k5 s2 p2, 55->28
  convT_k<16,32,16,5,2,2,55,55,28,28,0,7,36,false>
      <<<dim3(200,2), 252, 0, stream>>>(bufB, tw2T, tb2, nullptr,nullptr,nullptr,nullptr, bufA);
  pool_k<32,28,28><<<dim3(23328), blk, 0, stream>>>(bufA, bufB);   // ->[B,32,27,27]
  // conv3: 32->64 k3 s1 p1, 27 (VEC). rows=6912, GPR=7, RPB=36 -> 192 blocks
  convT_k<32,64,16,3,1,1,27,27,27,27,0,7,36,true>
      <<<dim3(192,4), 252, 0, stream>>>(bufB, tw3T, tb3, nullptr,nullptr,nullptr,nullptr, bufA);
  // conv4: 64->128 k3 s1 p1, 27 (VEC)
  convT_k<64,128,16,3,1,1,27,27,27,27,0,7,36,true>
      <<<dim3(192,8), 252, 0, stream>>>(bufA, tw4T, tb4, nullptr,nullptr,nullptr,nullptr, bufB);
  papool_k<<<dim3(1152), blk, 0, stream>>>(bufB, flat);

  // ---- MoE head (dense over 3 experts) ----
  gemm_k<1><<<dim3(16,4,3), blk, 0, stream>>>(flat, ew1, eb1, h1, 256, 1024, 1152, 0L);
  gemm_k<1><<<dim3( 8,4,3), blk, 0, stream>>>(h1,   ew2, eb2, h2, 256,  512, 1024, 256L*1024);
  gemm_k<0><<<dim3( 8,4,3), blk, 0, stream>>>(h2,   ew3, eb3, h3, 256,  512,  512, 256L*512);
  comb_k<<<dim3(512), blk, 0, stream>>>(h3, comb, out);
}

// Round 4
// 1522.269 us; speedup vs baseline: 1.7232x; 1.7232x over previous
//
#include <hip/hip_runtime.h>

#define DEV static __device__ __forceinline__

constexpr int BATCH = 256;

DEV float leakyf(float x){ return x > 0.f ? x : 0.2f * x; }

// 16B vector load with only 4B alignment guarantee (unaligned float4)
struct __attribute__((packed, aligned(4))) f4u { float x, y, z, w; };

// ---------------- weight transpose: w[OC][RED] -> wT[RED][OC] ----------------
__global__ __launch_bounds__(256) void kwT(const float* __restrict__ w,
                                           float* __restrict__ wt, int OC, int RED){
  int i = blockIdx.x * 256 + threadIdx.x;
  if (i >= OC * RED) return;
  int oc = i / RED, r = i % RED;
  wt[r * OC + oc] = w[i];
}

// ---------------- round-2 proven direct conv (low VGPR, no spill) -----------
// one thread = one (n,oh,ow), OCG channels. ACT: 0 bias+leaky, 1 bias+BN+relu
template<int IC,int OC,int OCG,int K,int S,int P,int IH,int IW,int OH,int OW,int ACT>
__global__ __launch_bounds__(256) void conv_k(
    const float* __restrict__ x, const float* __restrict__ wT,
    const float* __restrict__ bias,
    const float* __restrict__ bng, const float* __restrict__ bnb,
    const float* __restrict__ bnm, const float* __restrict__ bnv,
    float* __restrict__ out){
  constexpr int PIX = OH * OW;
  int idx = blockIdx.x * 256 + threadIdx.x;
  if (idx >= BATCH * PIX) return;
  int n = idx / PIX, p = idx % PIX;
  int oh = p / OW, ow = p % OW;
  int ocb = blockIdx.y * OCG;

  float acc[OCG];
  #pragma unroll
  for (int j = 0; j < OCG; ++j) acc[j] = 0.f;

  const float* xin = x + (size_t)n * IC * IH * IW;
  for (int ic = 0; ic < IC; ++ic){
    const float* xc = xin + (size_t)ic * IH * IW;
    #pragma unroll
    for (int kh = 0; kh < K; ++kh){
      int ih = oh * S - P + kh;
      bool rv = (ih >= 0) && (ih < IH);
      const float* xr = xc + (size_t)ih * IW;
      #pragma unroll
      for (int kw = 0; kw < K; ++kw){
        int iw = ow * S - P + kw;
        float v = (rv && iw >= 0 && iw < IW) ? xr[iw] : 0.f;
        const float* wrow = wT + (size_t)((ic * K + kh) * K + kw) * OC + ocb;
        #pragma unroll
        for (int j = 0; j < OCG; ++j) acc[j] += v * wrow[j];
      }
    }
  }

  #pragma unroll
  for (int j = 0; j < OCG; ++j){
    int oc = ocb + j;
    float val = acc[j] + bias[oc];
    if (ACT == 1){
      float scale = bng[oc] / sqrtf(bnv[oc] + 1e-5f);
      val = (val - bnm[oc]) * scale + bnb[oc];
      val = fmaxf(val, 0.f);
    } else {
      val = leakyf(val);
    }
    out[((size_t)(n * OC + oc) * OH + oh) * OW + ow] = val;
  }
}

// ---------------- register-blocked stride-1 K=3 conv (VEC) ------------------
// Each thread: 4 consecutive ow pixels x OCG channels; weights in LDS
// (uniform-address broadcast reads); one unaligned 8-float load per (ic,kh).
template<int IC,int OC,int OCG,int IH,int IW,int GPR,int RPB>
__global__ __launch_bounds__(256) void convV_k(
    const float* __restrict__ in, const float* __restrict__ wT,
    const float* __restrict__ bias, float* __restrict__ out){
  constexpr int K = 3, P = 1, OH = IH, OW = IW;
  constexpr int RED = IC * K * K;
  __shared__ float wlds[RED * OCG];

  const int tid = threadIdx.x;
  const int ocb = blockIdx.y * OCG;
  for (int i = tid; i < RED * OCG; i += GPR * RPB){
    int k = i / OCG, j = i % OCG;
    wlds[i] = wT[(size_t)k * OC + ocb + j];
  }
  __syncthreads();

  const int g = tid % GPR;
  const int r = tid / GPR;
  const int row = blockIdx.x * RPB + r;
  const bool trow = (row < BATCH * OH);
  const int n = row / OH, oh = row % OH;
  const int ow0 = 4 * g;

  float acc[4][OCG];
  #pragma unroll
  for (int e = 0; e < 4; ++e)
    #pragma unroll
    for (int j = 0; j < OCG; ++j) acc[e][j] = 0.f;

  for (int ic = 0; ic < IC; ++ic){
    const float* chan = in + ((size_t)n * IC + ic) * IH * IW;
    #pragma unroll
    for (int kh = 0; kh < K; ++kh){
      const int ih = oh - P + kh;
      const bool rv = trow && (ih >= 0) && (ih < IH);
      const float* rowp = chan + (long)ih * IW;

      float vv[8];
      if (rv){
        f4u lo = *reinterpret_cast<const f4u*>(rowp + ow0 - P);
        f4u hi = *reinterpret_cast<const f4u*>(rowp + ow0 - P + 4);
        vv[0]=lo.x; vv[1]=lo.y; vv[2]=lo.z; vv[3]=lo.w;
        vv[4]=hi.x; vv[5]=hi.y; vv[6]=hi.z; vv[7]=hi.w;
      } else {
        #pragma unroll
        for (int m = 0; m < 8; ++m) vv[m] = 0.f;
      }
      #pragma unroll
      for (int m = 0; m < K + 3; ++m){
        int iw = ow0 - P + m;
        if (iw < 0 || iw >= IW) vv[m] = 0.f;
      }
      #pragma unroll
      for (int kw = 0; kw < K; ++kw){
        const float* wr = &wlds[((ic * K + kh) * K + kw) * OCG];
        float w[OCG];
        #pragma unroll
        for (int q = 0; q < OCG / 4; ++q){
          float4 wq = *reinterpret_cast<const float4*>(wr + 4 * q);
          w[4*q+0]=wq.x; w[4*q+1]=wq.y; w[4*q+2]=wq.z; w[4*q+3]=wq.w;
        }
        #pragma unroll
        for (int e = 0; e < 4; ++e){
          float v = vv[kw + e];
          #pragma unroll
          for (int j = 0; j < OCG; ++j) acc[e][j] += v * w[j];
        }
      }
    }
  }

  if (!trow) return;
  #pragma unroll
  for (int j = 0; j < OCG; ++j){
    const int oc = ocb + j;
    const float b = bias[oc];
    float* op = out + ((size_t)(n * OC + oc) * OH + oh) * OW;
    #pragma unroll
    for (int e = 0; e < 4; ++e){
      const int ow = ow0 + e;
      if (ow >= OW) continue;
      op[ow] = leakyf(acc[e][j] + b);
    }
  }
}

// ---------------- 2x2 stride-1 maxpool ----------------
template<int C,int IH,int IW>
__global__ __launch_bounds__(256) void pool_k(const float* __restrict__ in,
                                              float* __restrict__ out){
  constexpr int OH = IH - 1, OW = IW - 1;
  int idx = blockIdx.x * 256 + threadIdx.x;
  if (idx >= BATCH * C * OH * OW) return;
  int ow = idx % OW; int t = idx / OW;
  int oh = t % OH;   t /= OH;
  const float* p = in + ((size_t)t * IH + oh) * IW + ow;
  out[idx] = fmaxf(fmaxf(p[0], p[1]), fmaxf(p[IW], p[IW + 1]));
}

// ---------------- scout gate ----------------
__global__ __launch_bounds__(256) void gate_k(const float* __restrict__ s2,
                                              const float* __restrict__ cw,
                                              const float* __restrict__ cb,
                                              float* __restrict__ comb){
  int n = blockIdx.x;
  int tid = threadIdx.x;
  int c = tid >> 3;
  int sub = tid & 7;
  const float* p = s2 + ((size_t)n * 32 + c) * 784;
  float s = 0.f;
  for (int i = sub * 98; i < sub * 98 + 98; ++i) s += p[i];
  __shared__ float red[32][8];
  red[c][sub] = s;
  __syncthreads();
  if (tid < 32){
    float tot = 0.f;
    #pragma unroll
    for (int k = 0; k < 8; ++k) tot += red[tid][k];
    red[tid][0] = tot / 784.f;
  }
  __syncthreads();
  if (tid == 0){
    float lg[3];
    for (int e = 0; e < 3; ++e){
      float a = cb[e];
      for (int c2 = 0; c2 < 32; ++c2) a += red[c2][0] * cw[e * 32 + c2];
      lg[e] = a;
    }
    float m = fmaxf(lg[0], fmaxf(lg[1], lg[2]));
    float ex[3], sum = 0.f;
    for (int e = 0; e < 3; ++e){ ex[e] = expf(lg[e] - m); sum += ex[e]; }
    float pr[3];
    for (int e = 0; e < 3; ++e) pr[e] = ex[e] / sum;
    int i1 = 0;
    if (pr[1] > pr[0]) i1 = 1;
    if (pr[2] > pr[i1]) i1 = 2;
    int i2 = -1;
    for (int e = 0; e < 3; ++e){
      if (e == i1) continue;
      if (i2 < 0 || pr[e] > pr[i2]) i2 = e;
    }
    float s12 = pr[i1] + pr[i2] + 1e-6f;
    float cmb[3] = {0.f, 0.f, 0.f};
    cmb[i1] = pr[i1] / s12;
    cmb[i2] = pr[i2] / s12;
    comb[n * 3 + 0] = cmb[0];
    comb[n * 3 + 1] = cmb[1];
    comb[n * 3 + 2] = cmb[2];
  }
}

// ------ fused maxpool2s1(27->26) + adaptive avg pool(26->3) -----------------
__global__ __launch_bounds__(256) void papool_k(const float* __restrict__ in,
                                                float* __restrict__ flat){
  int idx = blockIdx.x * 256 + threadIdx.x;
  if (idx >= BATCH * 128 * 9) return;
  int j = idx % 3; int t = idx / 3;
  int i = t % 3;   t /= 3;
  int c = t % 128; int n = t / 128;
  int hs = (i * 26) / 3, he = ((i + 1) * 26 + 2) / 3;
  int ws = (j * 26) / 3, we = ((j + 1) * 26 + 2) / 3;
  const float* p = in + ((size_t)n * 128 + c) * 729;
  float s = 0.f;
  for (int r = hs; r < he; ++r){
    const float* r0 = p + r * 27;
    const float* r1 = r0 + 27;
    for (int cc = ws; cc < we; ++cc){
      float m = fmaxf(fmaxf(r0[cc], r0[cc + 1]), fmaxf(r1[cc], r1[cc + 1]));
      s += m;
    }
  }
  flat[(size_t)n * 1152 + c * 9 + i * 3 + j] = s / (float)((he - hs) * (we - ws));
}

// ---------------- tiled GEMM: out[M,N] = A[M,K] * W[N,K]^T + bias -----------
template<int ACT>
__global__ __launch_bounds__(256) void gemm_k(const float* __restrict__ A,
                                              const float* __restrict__ W,
                                              const float* __restrict__ bias,
                                              float* __restrict__ out,
                                              int M, int N, int K, long strideA){
  int e = blockIdx.z;
  A += (size_t)e * strideA;
  W += (size_t)e * N * K;
  bias += e * N;
  out += (size_t)e * M * N;

  __shared__ float As[16][68];
  __shared__ float Bs[16][68];
  int tid = threadIdx.x;
  int m0 = blockIdx.y * 64, n0 = blockIdx.x * 64;
  int lr = tid >> 2;
  int lk = (tid & 3) * 4;
  int tx = tid & 15, ty = tid >> 4;
  float acc[4][4] = {};

  for (int k0 = 0; k0 < K; k0 += 16){
    float4 av = *(const float4*)&A[(size_t)(m0 + lr) * K + k0 + lk];
    float4 bv = *(const float4*)&W[(size_t)(n0 + lr) * K + k0 + lk];
    As[lk + 0][lr] = av.x; As[lk + 1][lr] = av.y;
    As[lk + 2][lr] = av.z; As[lk + 3][lr] = av.w;
    Bs[lk + 0][lr] = bv.x; Bs[lk + 1][lr] = bv.y;
    Bs[lk + 2][lr] = bv.z; Bs[lk + 3][lr] = bv.w;
    __syncthreads();
    #pragma unroll
    for (int k = 0; k < 16; ++k){
      float a[4], b[4];
      #pragma unroll
      for (int i = 0; i < 4; ++i) a[i] = As[k][ty * 4 + i];
      #pragma unroll
      for (int j = 0; j < 4; ++j) b[j] = Bs[k][tx * 4 + j];
      #pragma unroll
      for (int i = 0; i < 4; ++i)
        #pragma unroll
        for (int j = 0; j < 4; ++j) acc[i][j] += a[i] * b[j];
    }
    __syncthreads();
  }

  #pragma unroll
  for (int i = 0; i < 4; ++i){
    int m = m0 + ty * 4 + i;
    #pragma unroll
    for (int j = 0; j < 4; ++j){
      int nn = n0 + tx * 4 + j;
      float v = acc[i][j] + bias[nn];
      if (ACT == 1) v = leakyf(v);
      out[(size_t)m * N + nn] = v;
    }
  }
}

// ---------------- final gated combine ----------------
__global__ __launch_bounds__(256) void comb_k(const float* __restrict__ h3,
                                              const float* __restrict__ comb,
                                              float* __restrict__ out){
  int idx = blockIdx.x * 256 + threadIdx.x;
  if (idx >= BATCH * 512) return;
  int o = idx % 512, b = idx / 512;
  float s = 0.f;
  #pragma unroll
  for (int e = 0; e < 3; ++e)
    s += comb[b * 3 + e] * h3[((size_t)e * BATCH + b) * 512 + o];
  out[idx] = s;
}

// ============================================================================
extern "C" void kernel_launch(void* const* d_in, const int* in_sizes, int n_in,
                              void* d_out, int out_size, void* d_ws, size_t ws_size,
                              hipStream_t stream){
  const float* x    = (const float*)d_in[0];
  const float* tw1  = (const float*)d_in[1];  const float* tb1 = (const float*)d_in[2];
  const float* tw2  = (const float*)d_in[3];  const float* tb2 = (const float*)d_in[4];
  const float* tw3  = (const float*)d_in[5];  const float* tb3 = (const float*)d_in[6];
  const float* tw4  = (const float*)d_in[7];  const float* tb4 = (const float*)d_in[8];
  const float* sw1  = (const float*)d_in[9];  const float* sb1 = (const float*)d_in[10];
  const float* bn1g = (const float*)d_in[11]; const float* bn1b = (const float*)d_in[12];
  const float* bn1m = (const float*)d_in[13]; const float* bn1v = (const float*)d_in[14];
  const float* sw2  = (const float*)d_in[15]; const float* sb2 = (const float*)d_in[16];
  const float* bn2g = (const float*)d_in[17]; const float* bn2b = (const float*)d_in[18];
  const float* bn2m = (const float*)d_in[19]; const float* bn2v = (const float*)d_in[20];
  const float* cw   = (const float*)d_in[21]; const float* cb  = (const float*)d_in[22];
  const float* ew1  = (const float*)d_in[23]; const float* eb1 = (const float*)d_in[24];
  const float* ew2  = (const float*)d_in[25]; const float* eb2 = (const float*)d_in[26];
  const float* ew3  = (const float*)d_in[27]; const float* eb3 = (const float*)d_in[28];
  float* out = (float*)d_out;

  // ---- workspace layout (floats), ~154.5 MB ----
  float* ws = (float*)d_ws;
  size_t off = 0;
  float* comb  = ws + off; off += 768;
  float* tw1T  = ws + off; off += 16 * 27;
  float* tw2T  = ws + off; off += 32 * 400;
  float* tw3T  = ws + off; off += 64 * 288;
  float* tw4T  = ws + off; off += 128 * 576;
  float* sw1T  = ws + off; off += 16 * 147;
  float* sw2T  = ws + off; off += 32 * 144;
  float* flat  = ws + off; off += (size_t)BATCH * 1152;
  float* h1    = ws + off; off += (size_t)BATCH * 3 * 1024;
  float* h2    = ws + off; off += (size_t)BATCH * 3 * 512;
  float* h3    = ws + off; off += (size_t)BATCH * 3 * 512;
  off += 16;                                                    // guard pad
  float* bufA  = ws + off; off += (size_t)BATCH * 16 * 56 * 56;
  off += 16;                                                    // guard pad
  float* bufB  = ws + off; off += (size_t)BATCH * 128 * 27 * 27;
  off += 16;                                                    // guard pad
  (void)ws_size; (void)in_sizes; (void)n_in; (void)out_size;

  dim3 blk(256);

  // ---- transpose all conv weights to [red][OC] ----
  kwT<<<dim3(( 16*27 +255)/256), blk, 0, stream>>>(tw1, tw1T, 16, 27);
  kwT<<<dim3(( 32*400+255)/256), blk, 0, stream>>>(tw2, tw2T, 32, 400);
  kwT<<<dim3(( 64*288+255)/256), blk, 0, stream>>>(tw3, tw3T, 64, 288);
  kwT<<<dim3((128*576+255)/256), blk, 0, stream>>>(tw4, tw4T, 128, 576);
  kwT<<<dim3(( 16*147+255)/256), blk, 0, stream>>>(sw1, sw1T, 16, 147);
  kwT<<<dim3(( 32*144+255)/256), blk, 0, stream>>>(sw2, sw2T, 32, 144);

  // ---- scout router (round-2 proven conv_k) ----
  conv_k<3,16,16,7,4,3,224,224,56,56,1><<<dim3(3136,1), blk, 0, stream>>>(
      x, sw1T, sb1, bn1g, bn1b, bn1m, bn1v, bufA);
  conv_k<16,32,32,3,2,1,56,56,28,28,1><<<dim3(784,1), blk, 0, stream>>>(
      bufA, sw2T, sb2, bn2g, bn2b, bn2m, bn2v, bufB);
  gate_k<<<dim3(256), blk, 0, stream>>>(bufB, cw, cb, comb);

  // ---- trunk ----
  conv_k<3,16,16,3,4,1,224,224,56,56,0><<<dim3(3136,1), blk, 0, stream>>>(
      x, tw1T, tb1, nullptr, nullptr, nullptr, nullptr, bufA);
  pool_k<16,56,56><<<dim3(48400), blk, 0, stream>>>(bufA, bufB);   // ->[B,16,55,55]
  conv_k<16,32,32,5,2,2,55,55,28,28,0><<<dim3(784,1), blk, 0, stream>>>(
      bufB, tw2T, tb2, nullptr, nullptr, nullptr, nullptr, bufA);
  pool_k<32,28,28><<<dim3(23328), blk, 0, stream>>>(bufA, bufB);   // ->[B,32,27,27]
  // conv3/conv4: register-blocked VEC kernels (K=3, stride-1)
  convV_k<32,64,16,27,27,7,36>
      <<<dim3(192,4), 252, 0, stream>>>(bufB, tw3T, tb3, bufA);
  convV_k<64,128,16,27,27,7,36>
      <<<dim3(192,8), 252, 0, stream>>>(bufA, tw4T, tb4, bufB);
  papool_k<<<dim3(1152), blk, 0, stream>>>(bufB, flat);

  // ---- MoE head (dense over 3 experts) ----
  gemm_k<1><<<dim3(16,4,3), blk, 0, stream>>>(flat, ew1, eb1, h1, 256, 1024, 1152, 0L);
  gemm_k<1><<<dim3( 8,4,3), blk, 0, stream>>>(h1,   ew2, eb2, h2, 256,  512, 1024, 256L*1024);
  gemm_k<0><<<dim3( 8,4,3), blk, 0, stream>>>(h2,   ew3, eb3, h3, 256,  512,  512, 256L*512);
  comb_k<<<dim3(512), blk, 0, stream>>>(h3, comb, out);
}

// Round 5
// 1190.597 us; speedup vs baseline: 2.2033x; 1.2786x over previous
//
#include <hip/hip_runtime.h>

#define DEV static __device__ __forceinline__

constexpr int BATCH = 256;

DEV float leakyf(float x){ return x > 0.f ? x : 0.2f * x; }

typedef short bf16x8 __attribute__((ext_vector_type(8)));
typedef float f32x4 __attribute__((ext_vector_type(4)));

DEV unsigned short f2bf(float v){
  union { float f; unsigned u; } x; x.f = v;
  unsigned r = x.u + 0x7fffu + ((x.u >> 16) & 1u);
  return (unsigned short)(r >> 16);
}
DEV float bf2f(unsigned short b){
  union { unsigned u; float f; } x; x.u = ((unsigned)b) << 16;
  return x.f;
}

// ---------------- weight transpose: w[OC][RED] -> wT[RED][OC] ----------------
__global__ __launch_bounds__(256) void kwT(const float* __restrict__ w,
                                           float* __restrict__ wt, int OC, int RED){
  int i = blockIdx.x * 256 + threadIdx.x;
  if (i >= OC * RED) return;
  int oc = i / RED, r = i % RED;
  wt[r * OC + oc] = w[i];
}

// ------- pack OIHW weights into MFMA B-fragment order, split bf16 hi/lo -----
// frag id = (t*S + s)*F + f ; slot = lane*8 + j ; oc = f*16+(lane&15),
// ic = s*32+(lane>>4)*8+j ; t = kh*3+kw
template<int IC,int OC>
__global__ __launch_bounds__(256) void wpack_k(const float* __restrict__ w,
    unsigned short* __restrict__ hi, unsigned short* __restrict__ lo){
  constexpr int S = IC/32, F = OC/16;
  int i = blockIdx.x*256 + threadIdx.x;
  if (i >= 9*S*F*512) return;
  int j = i & 7, L = (i >> 3) & 63, rest = i >> 9;
  int f = rest % F; int q2 = rest / F; int s = q2 % S; int t = q2 / S;
  int oc = f*16 + (L & 15), ic = s*32 + (L >> 4)*8 + j;
  float v = w[((size_t)oc*IC + ic)*9 + t];
  unsigned short h = f2bf(v);
  hi[i] = h; lo[i] = f2bf(v - bf2f(h));
}

// ---------------- round-2 proven direct conv (low VGPR, no spill) -----------
template<int IC,int OC,int OCG,int K,int S,int P,int IH,int IW,int OH,int OW,int ACT>
__global__ __launch_bounds__(256) void conv_k(
    const float* __restrict__ x, const float* __restrict__ wT,
    const float* __restrict__ bias,
    const float* __restrict__ bng, const float* __restrict__ bnb,
    const float* __restrict__ bnm, const float* __restrict__ bnv,
    float* __restrict__ out){
  constexpr int PIX = OH * OW;
  int idx = blockIdx.x * 256 + threadIdx.x;
  if (idx >= BATCH * PIX) return;
  int n = idx / PIX, p = idx % PIX;
  int oh = p / OW, ow = p % OW;
  int ocb = blockIdx.y * OCG;

  float acc[OCG];
  #pragma unroll
  for (int j = 0; j < OCG; ++j) acc[j] = 0.f;

  const float* xin = x + (size_t)n * IC * IH * IW;
  for (int ic = 0; ic < IC; ++ic){
    const float* xc = xin + (size_t)ic * IH * IW;
    #pragma unroll
    for (int kh = 0; kh < K; ++kh){
      int ih = oh * S - P + kh;
      bool rv = (ih >= 0) && (ih < IH);
      const float* xr = xc + (size_t)ih * IW;
      #pragma unroll
      for (int kw = 0; kw < K; ++kw){
        int iw = ow * S - P + kw;
        float v = (rv && iw >= 0 && iw < IW) ? xr[iw] : 0.f;
        const float* wrow = wT + (size_t)((ic * K + kh) * K + kw) * OC + ocb;
        #pragma unroll
        for (int j = 0; j < OCG; ++j) acc[j] += v * wrow[j];
      }
    }
  }

  #pragma unroll
  for (int j = 0; j < OCG; ++j){
    int oc = ocb + j;
    float val = acc[j] + bias[oc];
    if (ACT == 1){
      float scale = bng[oc] / sqrtf(bnv[oc] + 1e-5f);
      val = (val - bnm[oc]) * scale + bnb[oc];
      val = fmaxf(val, 0.f);
    } else {
      val = leakyf(val);
    }
    out[((size_t)(n * OC + oc) * OH + oh) * OW + ow] = val;
  }
}

// ---------------- MFMA split-bf16 3x3 s1 p1 conv on 27x27, padded NHWC ------
// Input: padded [B][29][29][IC] bf16 hi/lo (zero borders). Block: (n, row-pair).
// 4 waves: wave w -> out row (oh0 + (w&1)), oc block (w>>1)*FW*16.
// OUTM 0: write leaky + re-split hi/lo to padded NHWC (for next conv)
// OUTM 1: write leaky fp32 NHWC [B][27][27][OC]
template<int IC,int OC,int OUTM>
__global__ __launch_bounds__(256) void convM_k(
    const unsigned short* __restrict__ Ahi_g, const unsigned short* __restrict__ Alo_g,
    const unsigned short* __restrict__ Whi, const unsigned short* __restrict__ Wlo,
    const float* __restrict__ bias,
    unsigned short* __restrict__ OutHi, unsigned short* __restrict__ OutLo,
    float* __restrict__ OutF)
{
  constexpr int S = IC/32, FTOT = OC/16, FW = FTOT/2;
  constexpr int ICB = IC*2, ICG = ICB/16;
  __shared__ __align__(16) char Ah[4*34*ICB];
  __shared__ __align__(16) char Al[4*34*ICB];

  const int tid = threadIdx.x;
  const int bx = blockIdx.x;
  const int n = bx / 14, pr = bx % 14;
  const int oh0 = pr * 2;

  // ---- stage A tile: padded rows oh0..oh0+3, 34 cols (29 real), XOR-swizzled
  const size_t gbase = ((size_t)n*29) * 29 * IC;
  for (int g = tid; g < 4*34*ICG; g += 256){
    int r = g / (34*ICG);
    int rem = g - r*(34*ICG);
    int c = rem / ICG, q = rem - c*ICG;
    int rp = oh0 + r;
    int4 vh = {0,0,0,0}, vl = {0,0,0,0};
    if (rp <= 28 && c < 29){
      size_t e = gbase + ((size_t)rp*29 + c)*IC + q*8;
      vh = *(const int4*)(Ahi_g + e);
      vl = *(const int4*)(Alo_g + e);
    }
    int off = (r*34 + c)*ICB + q*16;
    int swz = off ^ ((c & 7) << 4);
    *(int4*)(Ah + swz) = vh;
    *(int4*)(Al + swz) = vl;
  }
  __syncthreads();

  const int wid = tid >> 6, lane = tid & 63;
  const int rsel = wid & 1, ocq = wid >> 1;
  const int c0 = lane & 15, kg = (lane >> 4) * 16;
  const int colb0 = c0*ICB + kg, colb1 = (16 + c0)*ICB + kg;
  int msk[3];
  #pragma unroll
  for (int kw = 0; kw < 3; ++kw) msk[kw] = ((c0 + kw) & 7) << 4;

  f32x4 acc[2][FW];
  #pragma unroll
  for (int m = 0; m < 2; ++m)
    #pragma unroll
    for (int f = 0; f < FW; ++f) acc[m][f] = (f32x4){0.f,0.f,0.f,0.f};

  #pragma unroll
  for (int kh = 0; kh < 3; ++kh){
    #pragma unroll
    for (int kw = 0; kw < 3; ++kw){
      #pragma unroll
      for (int s = 0; s < S; ++s){
        const int fr0 = (((kh*3 + kw)*S + s)*FTOT + ocq*FW) * 512 + lane*8;
        bf16x8 bh[FW], bl[FW];
        #pragma unroll
        for (int f = 0; f < FW; ++f){
          bh[f] = *(const bf16x8*)(Whi + fr0 + f*512);
          bl[f] = *(const bf16x8*)(Wlo + fr0 + f*512);
        }
        const int base = ((rsel + kh)*34 + kw)*ICB + s*64;
        const int o0 = (base + colb0) ^ msk[kw];
        const int o1 = (base + colb1) ^ msk[kw];
        bf16x8 ah0 = *(const bf16x8*)(Ah + o0);
        bf16x8 al0 = *(const bf16x8*)(Al + o0);
        bf16x8 ah1 = *(const bf16x8*)(Ah + o1);
        bf16x8 al1 = *(const bf16x8*)(Al + o1);
        #pragma unroll
        for (int f = 0; f < FW; ++f){
          acc[0][f] = __builtin_amdgcn_mfma_f32_16x16x32_bf16(ah0, bh[f], acc[0][f], 0,0,0);
          acc[0][f] = __builtin_amdgcn_mfma_f32_16x16x32_bf16(ah0, bl[f], acc[0][f], 0,0,0);
          acc[0][f] = __builtin_amdgcn_mfma_f32_16x16x32_bf16(al0, bh[f], acc[0][f], 0,0,0);
          acc[1][f] = __builtin_amdgcn_mfma_f32_16x16x32_bf16(ah1, bh[f], acc[1][f], 0,0,0);
          acc[1][f] = __builtin_amdgcn_mfma_f32_16x16x32_bf16(ah1, bl[f], acc[1][f], 0,0,0);
          acc[1][f] = __builtin_amdgcn_mfma_f32_16x16x32_bf16(al1, bh[f], acc[1][f], 0,0,0);
        }
      }
    }
  }

  const int orow = oh0 + rsel;
  if (orow >= 27) return;
  #pragma unroll
  for (int f = 0; f < FW; ++f){
    const int oc = (ocq*FW + f)*16 + c0;
    const float bv = bias[oc];
    #pragma unroll
    for (int m = 0; m < 2; ++m){
      #pragma unroll
      for (int r = 0; r < 4; ++r){
        const int ow = m*16 + (lane >> 4)*4 + r;
        if (ow >= 27) continue;
        float v = leakyf(acc[m][f][r] + bv);
        if (OUTM == 0){
          size_t o = (((size_t)n*29 + orow+1)*29 + ow+1)*OC + oc;
          unsigned short h = f2bf(v);
          OutHi[o] = h;
          OutLo[o] = f2bf(v - bf2f(h));
        } else {
          OutF[(((size_t)n*27 + orow)*27 + ow)*OC + oc] = v;
        }
      }
    }
  }
}

// ---------------- 2x2 stride-1 maxpool (NCHW) ----------------
template<int C,int IH,int IW>
__global__ __launch_bounds__(256) void pool_k(const float* __restrict__ in,
                                              float* __restrict__ out){
  constexpr int OH = IH - 1, OW = IW - 1;
  int idx = blockIdx.x * 256 + threadIdx.x;
  if (idx >= BATCH * C * OH * OW) return;
  int ow = idx % OW; int t = idx / OW;
  int oh = t % OH;   t /= OH;
  const float* p = in + ((size_t)t * IH + oh) * IW + ow;
  out[idx] = fmaxf(fmaxf(p[0], p[1]), fmaxf(p[IW], p[IW + 1]));
}

// ------- pool2: NCHW fp32 [B,32,28,28] -> padded NHWC bf16 hi/lo [B,29,29,32]
__global__ __launch_bounds__(256) void pool2n_k(const float* __restrict__ in,
    unsigned short* __restrict__ hi, unsigned short* __restrict__ lo){
  int idx = blockIdx.x*256 + threadIdx.x;
  if (idx >= BATCH*27*27*32) return;
  int ic = idx & 31; int p = idx >> 5;
  int ow = p % 27; int t = p / 27; int oh = t % 27; int n = t / 27;
  const float* b = in + ((size_t)(n*32 + ic)*28 + oh)*28 + ow;
  float v = fmaxf(fmaxf(b[0], b[1]), fmaxf(b[28], b[29]));
  size_t o = (((size_t)n*29 + oh+1)*29 + ow+1)*32 + ic;
  unsigned short h = f2bf(v);
  hi[o] = h; lo[o] = f2bf(v - bf2f(h));
}

// ---------------- scout gate ----------------
__global__ __launch_bounds__(256) void gate_k(const float* __restrict__ s2,
                                              const float* __restrict__ cw,
                                              const float* __restrict__ cb,
                                              float* __restrict__ comb){
  int n = blockIdx.x;
  int tid = threadIdx.x;
  int c = tid >> 3;
  int sub = tid & 7;
  const float* p = s2 + ((size_t)n * 32 + c) * 784;
  float s = 0.f;
  for (int i = sub * 98; i < sub * 98 + 98; ++i) s += p[i];
  __shared__ float red[32][8];
  red[c][sub] = s;
  __syncthreads();
  if (tid < 32){
    float tot = 0.f;
    #pragma unroll
    for (int k = 0; k < 8; ++k) tot += red[tid][k];
    red[tid][0] = tot / 784.f;
  }
  __syncthreads();
  if (tid == 0){
    float lg[3];
    for (int e = 0; e < 3; ++e){
      float a = cb[e];
      for (int c2 = 0; c2 < 32; ++c2) a += red[c2][0] * cw[e * 32 + c2];
      lg[e] = a;
    }
    float m = fmaxf(lg[0], fmaxf(lg[1], lg[2]));
    float ex[3], sum = 0.f;
    for (int e = 0; e < 3; ++e){ ex[e] = expf(lg[e] - m); sum += ex[e]; }
    float pr[3];
    for (int e = 0; e < 3; ++e) pr[e] = ex[e] / sum;
    int i1 = 0;
    if (pr[1] > pr[0]) i1 = 1;
    if (pr[2] > pr[i1]) i1 = 2;
    int i2 = -1;
    for (int e = 0; e < 3; ++e){
      if (e == i1) continue;
      if (i2 < 0 || pr[e] > pr[i2]) i2 = e;
    }
    float s12 = pr[i1] + pr[i2] + 1e-6f;
    float cmb[3] = {0.f, 0.f, 0.f};
    cmb[i1] = pr[i1] / s12;
    cmb[i2] = pr[i2] / s12;
    comb[n * 3 + 0] = cmb[0];
    comb[n * 3 + 1] = cmb[1];
    comb[n * 3 + 2] = cmb[2];
  }
}

// ------ fused maxpool2s1(27->26) + adaptive avg(26->3), NHWC input ----------
__global__ __launch_bounds__(256) void papooln_k(const float* __restrict__ in,
                                                 float* __restrict__ flat){
  int idx = blockIdx.x * 256 + threadIdx.x;
  if (idx >= BATCH * 128 * 9) return;
  int j = idx % 3; int t = idx / 3;
  int i = t % 3;   t /= 3;
  int c = t % 128; int n = t / 128;
  int hs = (i * 26) / 3, he = ((i + 1) * 26 + 2) / 3;
  int ws = (j * 26) / 3, we = ((j + 1) * 26 + 2) / 3;
  const float* p = in + (size_t)n * 729 * 128 + c;
  float s = 0.f;
  for (int r = hs; r < he; ++r)
    for (int cc = ws; cc < we; ++cc){
      const float* q0 = p + (r * 27 + cc) * 128;
      const float* q1 = q0 + 27 * 128;
      float m = fmaxf(fmaxf(q0[0], q0[128]), fmaxf(q1[0], q1[128]));
      s += m;
    }
  flat[(size_t)n * 1152 + c * 9 + i * 3 + j] = s / (float)((he - hs) * (we - ws));
}

// ---------------- tiled GEMM: out[M,N] = A[M,K] * W[N,K]^T + bias -----------
template<int ACT>
__global__ __launch_bounds__(256) void gemm_k(const float* __restrict__ A,
                                              const float* __restrict__ W,
                                              const float* __restrict__ bias,
                                              float* __restrict__ out,
                                              int M, int N, int K, long strideA){
  int e = blockIdx.z;
  A += (size_t)e * strideA;
  W += (size_t)e * N * K;
  bias += e * N;
  out += (size_t)e * M * N;

  __shared__ float As[16][68];
  __shared__ float Bs[16][68];
  int tid = threadIdx.x;
  int m0 = blockIdx.y * 64, n0 = blockIdx.x * 64;
  int lr = tid >> 2;
  int lk = (tid & 3) * 4;
  int tx = tid & 15, ty = tid >> 4;
  float acc[4][4] = {};

  for (int k0 = 0; k0 < K; k0 += 16){
    float4 av = *(const float4*)&A[(size_t)(m0 + lr) * K + k0 + lk];
    float4 bv = *(const float4*)&W[(size_t)(n0 + lr) * K + k0 + lk];
    As[lk + 0][lr] = av.x; As[lk + 1][lr] = av.y;
    As[lk + 2][lr] = av.z; As[lk + 3][lr] = av.w;
    Bs[lk + 0][lr] = bv.x; Bs[lk + 1][lr] = bv.y;
    Bs[lk + 2][lr] = bv.z; Bs[lk + 3][lr] = bv.w;
    __syncthreads();
    #pragma unroll
    for (int k = 0; k < 16; ++k){
      float a[4], b[4];
      #pragma unroll
      for (int i = 0; i < 4; ++i) a[i] = As[k][ty * 4 + i];
      #pragma unroll
      for (int j = 0; j < 4; ++j) b[j] = Bs[k][tx * 4 + j];
      #pragma unroll
      for (int i = 0; i < 4; ++i)
        #pragma unroll
        for (int j = 0; j < 4; ++j) acc[i][j] += a[i] * b[j];
    }
    __syncthreads();
  }

  #pragma unroll
  for (int i = 0; i < 4; ++i){
    int m = m0 + ty * 4 + i;
    #pragma unroll
    for (int j = 0; j < 4; ++j){
      int nn = n0 + tx * 4 + j;
      float v = acc[i][j] + bias[nn];
      if (ACT == 1) v = leakyf(v);
      out[(size_t)m * N + nn] = v;
    }
  }
}

// ---------------- final gated combine ----------------
__global__ __launch_bounds__(256) void comb_k(const float* __restrict__ h3,
                                              const float* __restrict__ comb,
                                              float* __restrict__ out){
  int idx = blockIdx.x * 256 + threadIdx.x;
  if (idx >= BATCH * 512) return;
  int o = idx % 512, b = idx / 512;
  float s = 0.f;
  #pragma unroll
  for (int e = 0; e < 3; ++e)
    s += comb[b * 3 + e] * h3[((size_t)e * BATCH + b) * 512 + o];
  out[idx] = s;
}

// ============================================================================
extern "C" void kernel_launch(void* const* d_in, const int* in_sizes, int n_in,
                              void* d_out, int out_size, void* d_ws, size_t ws_size,
                              hipStream_t stream){
  const float* x    = (const float*)d_in[0];
  const float* tw1  = (const float*)d_in[1];  const float* tb1 = (const float*)d_in[2];
  const float* tw2  = (const float*)d_in[3];  const float* tb2 = (const float*)d_in[4];
  const float* tw3  = (const float*)d_in[5];  const float* tb3 = (const float*)d_in[6];
  const float* tw4  = (const float*)d_in[7];  const float* tb4 = (const float*)d_in[8];
  const float* sw1  = (const float*)d_in[9];  const float* sb1 = (const float*)d_in[10];
  const float* bn1g = (const float*)d_in[11]; const float* bn1b = (const float*)d_in[12];
  const float* bn1m = (const float*)d_in[13]; const float* bn1v = (const float*)d_in[14];
  const float* sw2  = (const float*)d_in[15]; const float* sb2 = (const float*)d_in[16];
  const float* bn2g = (const float*)d_in[17]; const float* bn2b = (const float*)d_in[18];
  const float* bn2m = (const float*)d_in[19]; const float* bn2v = (const float*)d_in[20];
  const float* cw   = (const float*)d_in[21]; const float* cb  = (const float*)d_in[22];
  const float* ew1  = (const float*)d_in[23]; const float* eb1 = (const float*)d_in[24];
  const float* ew2  = (const float*)d_in[25]; const float* eb2 = (const float*)d_in[26];
  const float* ew3  = (const float*)d_in[27]; const float* eb3 = (const float*)d_in[28];
  float* out = (float*)d_out;

  // ---- workspace layout (floats), ~158.6 MB ----
  float* ws = (float*)d_ws;
  size_t off = 0;
  float* comb   = ws + off; off += 768;
  float* tw1T   = ws + off; off += 16 * 27;
  float* tw2T   = ws + off; off += 32 * 400;
  float* sw1T   = ws + off; off += 16 * 147;   // 2352
  float* sw2T   = ws + off; off += 32 * 144;   // 4608
  float* flat   = ws + off; off += (size_t)BATCH * 1152;
  float* h1     = ws + off; off += (size_t)BATCH * 3 * 1024;
  float* h2     = ws + off; off += (size_t)BATCH * 3 * 512;
  float* h3     = ws + off; off += (size_t)BATCH * 3 * 512;
  unsigned short* wpk3h = (unsigned short*)(ws + off); off += 9216;   // 18432 ushort
  unsigned short* wpk3l = (unsigned short*)(ws + off); off += 9216;
  unsigned short* wpk4h = (unsigned short*)(ws + off); off += 36864;  // 73728 ushort
  unsigned short* wpk4l = (unsigned short*)(ws + off); off += 36864;
  off += 16;                                                      // guard pad
  float* bufA   = ws + off; off += 13778944;  // scout1/conv1 out, conv2 out, C3 alias
  off += 16;                                                      // guard pad
  float* bufB   = ws + off; off += 23887872;  // scout2/pool1 out, P2 alias, conv4 out
  off += 16;
  (void)ws_size; (void)in_sizes; (void)n_in; (void)out_size;

  // aliases (lifetimes are disjoint, see launch order)
  unsigned short* C3h = (unsigned short*)bufA;                 // 13,778,944 ushort
  unsigned short* C3l = C3h + (size_t)13778944;
  unsigned short* P2h = (unsigned short*)bufB;                 // 6,889,472 ushort
  unsigned short* P2l = P2h + (size_t)6889472;

  dim3 blk(256);

  // ---- weight prep ----
  kwT<<<dim3(( 16*27 +255)/256), blk, 0, stream>>>(tw1, tw1T, 16, 27);
  kwT<<<dim3(( 32*400+255)/256), blk, 0, stream>>>(tw2, tw2T, 32, 400);
  kwT<<<dim3(( 16*147+255)/256), blk, 0, stream>>>(sw1, sw1T, 16, 147);
  kwT<<<dim3(( 32*144+255)/256), blk, 0, stream>>>(sw2, sw2T, 32, 144);
  wpack_k<32,64>  <<<dim3(72),  blk, 0, stream>>>(tw3, wpk3h, wpk3l);
  wpack_k<64,128> <<<dim3(288), blk, 0, stream>>>(tw4, wpk4h, wpk4l);

  // ---- scout router ----
  conv_k<3,16,16,7,4,3,224,224,56,56,1><<<dim3(3136,1), blk, 0, stream>>>(
      x, sw1T, sb1, bn1g, bn1b, bn1m, bn1v, bufA);
  conv_k<16,32,32,3,2,1,56,56,28,28,1><<<dim3(784,1), blk, 0, stream>>>(
      bufA, sw2T, sb2, bn2g, bn2b, bn2m, bn2v, bufB);
  gate_k<<<dim3(256), blk, 0, stream>>>(bufB, cw, cb, comb);

  // ---- trunk front ----
  conv_k<3,16,16,3,4,1,224,224,56,56,0><<<dim3(3136,1), blk, 0, stream>>>(
      x, tw1T, tb1, nullptr, nullptr, nullptr, nullptr, bufA);
  pool_k<16,56,56><<<dim3(48400), blk, 0, stream>>>(bufA, bufB);   // ->[B,16,55,55]
  conv_k<16,32,32,5,2,2,55,55,28,28,0><<<dim3(784,1), blk, 0, stream>>>(
      bufB, tw2T, tb2, nullptr, nullptr, nullptr, nullptr, bufA);

  // ---- pool2 -> padded NHWC bf16 hi/lo ----
  hipMemsetAsync(bufB, 0, (size_t)2 * 6889472 * 2, stream);        // P2 zero (borders)
  pool2n_k<<<dim3((BATCH*27*27*32 + 255)/256), blk, 0, stream>>>(bufA, P2h, P2l);

  // ---- conv3 (MFMA) -> padded NHWC bf16 hi/lo ----
  hipMemsetAsync(bufA, 0, (size_t)2 * 13778944 * 2, stream);       // C3 zero (borders)
  convM_k<32,64,0><<<dim3(BATCH*14), blk, 0, stream>>>(
      P2h, P2l, wpk3h, wpk3l, tb3, C3h, C3l, nullptr);

  // ---- conv4 (MFMA) -> fp32 NHWC [B,27,27,128] in bufB ----
  convM_k<64,128,1><<<dim3(BATCH*14), blk, 0, stream>>>(
      C3h, C3l, wpk4h, wpk4l, tb4, nullptr, nullptr, bufB);

  papooln_k<<<dim3(1152), blk, 0, stream>>>(bufB, flat);

  // ---- MoE head (dense over 3 experts) ----
  gemm_k<1><<<dim3(16,4,3), blk, 0, stream>>>(flat, ew1, eb1, h1, 256, 1024, 1152, 0L);
  gemm_k<1><<<dim3( 8,4,3), blk, 0, stream>>>(h1,   ew2, eb2, h2, 256,  512, 1024, 256L*1024);
  gemm_k<0><<<dim3( 8,4,3), blk, 0, stream>>>(h2,   ew3, eb3, h3, 256,  512,  512, 256L*512);
  comb_k<<<dim3(512), blk, 0, stream>>>(h3, comb, out);
}

// Round 6
// 1020.198 us; speedup vs baseline: 2.5713x; 1.1670x over previous
//
#include <hip/hip_runtime.h>

#define DEV static __device__ __forceinline__

constexpr int BATCH = 256;

DEV float leakyf(float x){ return x > 0.f ? x : 0.2f * x; }

typedef short bf16x8 __attribute__((ext_vector_type(8)));
typedef float f32x4 __attribute__((ext_vector_type(4)));

DEV unsigned short f2bf(float v){
  union { float f; unsigned u; } x; x.f = v;
  unsigned r = x.u + 0x7fffu + ((x.u >> 16) & 1u);
  return (unsigned short)(r >> 16);
}
DEV float bf2f(unsigned short b){
  union { unsigned u; float f; } x; x.u = ((unsigned)b) << 16;
  return x.f;
}

// ---------------- weight transpose: w[OC][RED] -> wT[RED][OC] ----------------
__global__ __launch_bounds__(256) void kwT(const float* __restrict__ w,
                                           float* __restrict__ wt, int OC, int RED){
  int i = blockIdx.x * 256 + threadIdx.x;
  if (i >= OC * RED) return;
  int oc = i / RED, r = i % RED;
  wt[r * OC + oc] = w[i];
}

// ------- pack OIHW conv weights into MFMA B-fragment order, bf16 hi/lo ------
template<int IC,int OC>
__global__ __launch_bounds__(256) void wpack_k(const float* __restrict__ w,
    unsigned short* __restrict__ hi, unsigned short* __restrict__ lo){
  constexpr int S = IC/32, F = OC/16;
  int i = blockIdx.x*256 + threadIdx.x;
  if (i >= 9*S*F*512) return;
  int j = i & 7, L = (i >> 3) & 63, rest = i >> 9;
  int f = rest % F; int q2 = rest / F; int s = q2 % S; int t = q2 / S;
  int oc = f*16 + (L & 15), ic = s*32 + (L >> 4)*8 + j;
  float v = w[((size_t)oc*IC + ic)*9 + t];
  unsigned short h = f2bf(v);
  hi[i] = h; lo[i] = f2bf(v - bf2f(h));
}

// ------- pack expert GEMM weights W[e][N][K] into frag order, bf16 hi/lo ----
template<int KTOT>
__global__ __launch_bounds__(256) void wpackG_k(const float* __restrict__ w, int N,
    unsigned short* __restrict__ hi, unsigned short* __restrict__ lo){
  const int NF = N >> 4, KT = KTOT >> 5;
  const int total = NF * KT * 512;
  const int e = blockIdx.y;
  w  += (size_t)e * N * KTOT;
  hi += (size_t)e * total; lo += (size_t)e * total;
  int i = blockIdx.x*256 + threadIdx.x;
  if (i >= total) return;
  int j = i & 7, L = (i >> 3) & 63, rest = i >> 9;
  int nf = rest % NF, t = rest / NF;
  int n = nf*16 + (L & 15), k = t*32 + (L >> 4)*8 + j;
  float v = w[(size_t)n*KTOT + k];
  unsigned short h = f2bf(v);
  hi[i] = h; lo[i] = f2bf(v - bf2f(h));
}

// ------- split fp32 array into bf16 hi/lo ----------------------------------
__global__ __launch_bounds__(256) void asplit_k(const float* __restrict__ in,
    unsigned short* __restrict__ hi, unsigned short* __restrict__ lo, int nelem){
  int i = blockIdx.x*256 + threadIdx.x;
  if (i >= nelem) return;
  float v = in[i];
  unsigned short h = f2bf(v);
  hi[i] = h; lo[i] = f2bf(v - bf2f(h));
}

// ---------------- round-2 proven direct conv (low VGPR, no spill) -----------
template<int IC,int OC,int OCG,int K,int S,int P,int IH,int IW,int OH,int OW,int ACT>
__global__ __launch_bounds__(256) void conv_k(
    const float* __restrict__ x, const float* __restrict__ wT,
    const float* __restrict__ bias,
    const float* __restrict__ bng, const float* __restrict__ bnb,
    const float* __restrict__ bnm, const float* __restrict__ bnv,
    float* __restrict__ out){
  constexpr int PIX = OH * OW;
  int idx = blockIdx.x * 256 + threadIdx.x;
  if (idx >= BATCH * PIX) return;
  int n = idx / PIX, p = idx % PIX;
  int oh = p / OW, ow = p % OW;
  int ocb = blockIdx.y * OCG;

  float acc[OCG];
  #pragma unroll
  for (int j = 0; j < OCG; ++j) acc[j] = 0.f;

  const float* xin = x + (size_t)n * IC * IH * IW;
  for (int ic = 0; ic < IC; ++ic){
    const float* xc = xin + (size_t)ic * IH * IW;
    #pragma unroll
    for (int kh = 0; kh < K; ++kh){
      int ih = oh * S - P + kh;
      bool rv = (ih >= 0) && (ih < IH);
      const float* xr = xc + (size_t)ih * IW;
      #pragma unroll
      for (int kw = 0; kw < K; ++kw){
        int iw = ow * S - P + kw;
        float v = (rv && iw >= 0 && iw < IW) ? xr[iw] : 0.f;
        const float* wrow = wT + (size_t)((ic * K + kh) * K + kw) * OC + ocb;
        #pragma unroll
        for (int j = 0; j < OCG; ++j) acc[j] += v * wrow[j];
      }
    }
  }

  #pragma unroll
  for (int j = 0; j < OCG; ++j){
    int oc = ocb + j;
    float val = acc[j] + bias[oc];
    if (ACT == 1){
      float scale = bng[oc] / sqrtf(bnv[oc] + 1e-5f);
      val = (val - bnm[oc]) * scale + bnb[oc];
      val = fmaxf(val, 0.f);
    } else {
      val = leakyf(val);
    }
    out[((size_t)(n * OC + oc) * OH + oh) * OW + ow] = val;
  }
}

// ---------------- MFMA split-bf16 3x3 s1 p1 conv on 27x27, padded NHWC ------
template<int IC,int OC,int OUTM>
__global__ __launch_bounds__(256) void convM_k(
    const unsigned short* __restrict__ Ahi_g, const unsigned short* __restrict__ Alo_g,
    const unsigned short* __restrict__ Whi, const unsigned short* __restrict__ Wlo,
    const float* __restrict__ bias,
    unsigned short* __restrict__ OutHi, unsigned short* __restrict__ OutLo,
    float* __restrict__ OutF)
{
  constexpr int S = IC/32, FTOT = OC/16, FW = FTOT/2;
  constexpr int ICB = IC*2, ICG = ICB/16;
  __shared__ __align__(16) char Ah[4*34*ICB];
  __shared__ __align__(16) char Al[4*34*ICB];

  const int tid = threadIdx.x;
  const int bx = blockIdx.x;
  const int n = bx / 14, pr = bx % 14;
  const int oh0 = pr * 2;

  const size_t gbase = ((size_t)n*29) * 29 * IC;
  for (int g = tid; g < 4*34*ICG; g += 256){
    int r = g / (34*ICG);
    int rem = g - r*(34*ICG);
    int c = rem / ICG, q = rem - c*ICG;
    int rp = oh0 + r;
    int4 vh = {0,0,0,0}, vl = {0,0,0,0};
    if (rp <= 28 && c < 29){
      size_t e = gbase + ((size_t)rp*29 + c)*IC + q*8;
      vh = *(const int4*)(Ahi_g + e);
      vl = *(const int4*)(Alo_g + e);
    }
    int off = (r*34 + c)*ICB + q*16;
    int swz = off ^ ((c & 7) << 4);
    *(int4*)(Ah + swz) = vh;
    *(int4*)(Al + swz) = vl;
  }
  __syncthreads();

  const int wid = tid >> 6, lane = tid & 63;
  const int rsel = wid & 1, ocq = wid >> 1;
  const int c0 = lane & 15, kg = (lane >> 4) * 16;
  const int colb0 = c0*ICB + kg, colb1 = (16 + c0)*ICB + kg;
  int msk[3];
  #pragma unroll
  for (int kw = 0; kw < 3; ++kw) msk[kw] = ((c0 + kw) & 7) << 4;

  f32x4 acc[2][FW];
  #pragma unroll
  for (int m = 0; m < 2; ++m)
    #pragma unroll
    for (int f = 0; f < FW; ++f) acc[m][f] = (f32x4){0.f,0.f,0.f,0.f};

  #pragma unroll
  for (int kh = 0; kh < 3; ++kh){
    #pragma unroll
    for (int kw = 0; kw < 3; ++kw){
      #pragma unroll
      for (int s = 0; s < S; ++s){
        const int fr0 = (((kh*3 + kw)*S + s)*FTOT + ocq*FW) * 512 + lane*8;
        bf16x8 bh[FW], bl[FW];
        #pragma unroll
        for (int f = 0; f < FW; ++f){
          bh[f] = *(const bf16x8*)(Whi + fr0 + f*512);
          bl[f] = *(const bf16x8*)(Wlo + fr0 + f*512);
        }
        const int base = ((rsel + kh)*34 + kw)*ICB + s*64;
        const int o0 = (base + colb0) ^ msk[kw];
        const int o1 = (base + colb1) ^ msk[kw];
        bf16x8 ah0 = *(const bf16x8*)(Ah + o0);
        bf16x8 al0 = *(const bf16x8*)(Al + o0);
        bf16x8 ah1 = *(const bf16x8*)(Ah + o1);
        bf16x8 al1 = *(const bf16x8*)(Al + o1);
        #pragma unroll
        for (int f = 0; f < FW; ++f){
          acc[0][f] = __builtin_amdgcn_mfma_f32_16x16x32_bf16(ah0, bh[f], acc[0][f], 0,0,0);
          acc[0][f] = __builtin_amdgcn_mfma_f32_16x16x32_bf16(ah0, bl[f], acc[0][f], 0,0,0);
          acc[0][f] = __builtin_amdgcn_mfma_f32_16x16x32_bf16(al0, bh[f], acc[0][f], 0,0,0);
          acc[1][f] = __builtin_amdgcn_mfma_f32_16x16x32_bf16(ah1, bh[f], acc[1][f], 0,0,0);
          acc[1][f] = __builtin_amdgcn_mfma_f32_16x16x32_bf16(ah1, bl[f], acc[1][f], 0,0,0);
          acc[1][f] = __builtin_amdgcn_mfma_f32_16x16x32_bf16(al1, bh[f], acc[1][f], 0,0,0);
        }
      }
    }
  }

  const int orow = oh0 + rsel;
  if (orow >= 27) return;
  #pragma unroll
  for (int f = 0; f < FW; ++f){
    const int oc = (ocq*FW + f)*16 + c0;
    const float bv = bias[oc];
    #pragma unroll
    for (int m = 0; m < 2; ++m){
      #pragma unroll
      for (int r = 0; r < 4; ++r){
        const int ow = m*16 + (lane >> 4)*4 + r;
        if (ow >= 27) continue;
        float v = leakyf(acc[m][f][r] + bv);
        if (OUTM == 0){
          size_t o = (((size_t)n*29 + orow+1)*29 + ow+1)*OC + oc;
          unsigned short h = f2bf(v);
          OutHi[o] = h;
          OutLo[o] = f2bf(v - bf2f(h));
        } else {
          OutF[(((size_t)n*27 + orow)*27 + ow)*OC + oc] = v;
        }
      }
    }
  }
}

// ---------------- split-bf16 MFMA GEMM for MoE head -------------------------
// C[e][256][N] = A[e][256][KTOT] * W[e][N][KTOT]^T + bias[e][N]
// block: 256 thr = 4 waves; tile M=32 x N=64 (wave -> one N-frag, 2 M-frags)
template<int KTOT,int ACT,int OUTM>
__global__ __launch_bounds__(256) void gemmM_k(
    const unsigned short* __restrict__ Ah, const unsigned short* __restrict__ Al,
    long strideA,
    const unsigned short* __restrict__ Wh, const unsigned short* __restrict__ Wl,
    const float* __restrict__ bias, int N,
    unsigned short* __restrict__ OutH, unsigned short* __restrict__ OutL,
    float* __restrict__ OutF){
  const int e = blockIdx.z;
  Ah += (size_t)e * strideA; Al += (size_t)e * strideA;
  const int NF = N >> 4, KT = KTOT >> 5;
  const size_t wb = (size_t)e * NF * KT * 512;
  Wh += wb; Wl += wb;
  const float* bs = bias + (size_t)e * N;
  const size_t ob = (size_t)e * 256 * N;

  const int tid = threadIdx.x, wid = tid >> 6, lane = tid & 63;
  const int mblk = blockIdx.x * 32;
  const int nf = blockIdx.y * 4 + wid;
  const int r0 = mblk + (lane & 15);
  const int kof = (lane >> 4) * 8;

  f32x4 acc0 = {0,0,0,0}, acc1 = {0,0,0,0};
  for (int t = 0; t < KT; ++t){
    const int k = t*32 + kof;
    bf16x8 ah0 = *(const bf16x8*)(Ah + (size_t)r0*KTOT + k);
    bf16x8 al0 = *(const bf16x8*)(Al + (size_t)r0*KTOT + k);
    bf16x8 ah1 = *(const bf16x8*)(Ah + (size_t)(r0+16)*KTOT + k);
    bf16x8 al1 = *(const bf16x8*)(Al + (size_t)(r0+16)*KTOT + k);
    const size_t fb = ((size_t)t*NF + nf)*512 + lane*8;
    bf16x8 bh = *(const bf16x8*)(Wh + fb);
    bf16x8 bl = *(const bf16x8*)(Wl + fb);
    acc0 = __builtin_amdgcn_mfma_f32_16x16x32_bf16(ah0, bh, acc0, 0,0,0);
    acc0 = __builtin_amdgcn_mfma_f32_16x16x32_bf16(ah0, bl, acc0, 0,0,0);
    acc0 = __builtin_amdgcn_mfma_f32_16x16x32_bf16(al0, bh, acc0, 0,0,0);
    acc1 = __builtin_amdgcn_mfma_f32_16x16x32_bf16(ah1, bh, acc1, 0,0,0);
    acc1 = __builtin_amdgcn_mfma_f32_16x16x32_bf16(ah1, bl, acc1, 0,0,0);
    acc1 = __builtin_amdgcn_mfma_f32_16x16x32_bf16(al1, bh, acc1, 0,0,0);
  }
  const int n = nf*16 + (lane & 15);
  const float bv = bs[n];
  #pragma unroll
  for (int mi = 0; mi < 2; ++mi){
    f32x4 a = mi ? acc1 : acc0;
    #pragma unroll
    for (int r = 0; r < 4; ++r){
      const int m = mblk + mi*16 + (lane >> 4)*4 + r;
      float v = a[r] + bv;
      if (ACT == 1) v = leakyf(v);
      const size_t o = ob + (size_t)m*N + n;
      if (OUTM == 0){
        unsigned short h = f2bf(v);
        OutH[o] = h; OutL[o] = f2bf(v - bf2f(h));
      } else {
        OutF[o] = v;
      }
    }
  }
}

// ---------------- 2x2 stride-1 maxpool (NCHW) ----------------
template<int C,int IH,int IW>
__global__ __launch_bounds__(256) void pool_k(const float* __restrict__ in,
                                              float* __restrict__ out){
  constexpr int OH = IH - 1, OW = IW - 1;
  int idx = blockIdx.x * 256 + threadIdx.x;
  if (idx >= BATCH * C * OH * OW) return;
  int ow = idx % OW; int t = idx / OW;
  int oh = t % OH;   t /= OH;
  const float* p = in + ((size_t)t * IH + oh) * IW + ow;
  out[idx] = fmaxf(fmaxf(p[0], p[1]), fmaxf(p[IW], p[IW + 1]));
}

// ------- pool2: NCHW fp32 [B,32,28,28] -> padded NHWC bf16 hi/lo [B,29,29,32]
__global__ __launch_bounds__(256) void pool2n_k(const float* __restrict__ in,
    unsigned short* __restrict__ hi, unsigned short* __restrict__ lo){
  int idx = blockIdx.x*256 + threadIdx.x;
  if (idx >= BATCH*27*27*32) return;
  int ic = idx & 31; int p = idx >> 5;
  int ow = p % 27; int t = p / 27; int oh = t % 27; int n = t / 27;
  const float* b = in + ((size_t)(n*32 + ic)*28 + oh)*28 + ow;
  float v = fmaxf(fmaxf(b[0], b[1]), fmaxf(b[28], b[29]));
  size_t o = (((size_t)n*29 + oh+1)*29 + ow+1)*32 + ic;
  unsigned short h = f2bf(v);
  hi[o] = h; lo[o] = f2bf(v - bf2f(h));
}

// ---------------- scout gate ----------------
__global__ __launch_bounds__(256) void gate_k(const float* __restrict__ s2,
                                              const float* __restrict__ cw,
                                              const float* __restrict__ cb,
                                              float* __restrict__ comb){
  int n = blockIdx.x;
  int tid = threadIdx.x;
  int c = tid >> 3;
  int sub = tid & 7;
  const float* p = s2 + ((size_t)n * 32 + c) * 784;
  float s = 0.f;
  for (int i = sub * 98; i < sub * 98 + 98; ++i) s += p[i];
  __shared__ float red[32][8];
  red[c][sub] = s;
  __syncthreads();
  if (tid < 32){
    float tot = 0.f;
    #pragma unroll
    for (int k = 0; k < 8; ++k) tot += red[tid][k];
    red[tid][0] = tot / 784.f;
  }
  __syncthreads();
  if (tid == 0){
    float lg[3];
    for (int e = 0; e < 3; ++e){
      float a = cb[e];
      for (int c2 = 0; c2 < 32; ++c2) a += red[c2][0] * cw[e * 32 + c2];
      lg[e] = a;
    }
    float m = fmaxf(lg[0], fmaxf(lg[1], lg[2]));
    float ex[3], sum = 0.f;
    for (int e = 0; e < 3; ++e){ ex[e] = expf(lg[e] - m); sum += ex[e]; }
    float pr[3];
    for (int e = 0; e < 3; ++e) pr[e] = ex[e] / sum;
    int i1 = 0;
    if (pr[1] > pr[0]) i1 = 1;
    if (pr[2] > pr[i1]) i1 = 2;
    int i2 = -1;
    for (int e = 0; e < 3; ++e){
      if (e == i1) continue;
      if (i2 < 0 || pr[e] > pr[i2]) i2 = e;
    }
    float s12 = pr[i1] + pr[i2] + 1e-6f;
    float cmb[3] = {0.f, 0.f, 0.f};
    cmb[i1] = pr[i1] / s12;
    cmb[i2] = pr[i2] / s12;
    comb[n * 3 + 0] = cmb[0];
    comb[n * 3 + 1] = cmb[1];
    comb[n * 3 + 2] = cmb[2];
  }
}

// ------ fused maxpool2s1(27->26) + adaptive avg(26->3), NHWC input ----------
__global__ __launch_bounds__(256) void papooln_k(const float* __restrict__ in,
                                                 float* __restrict__ flat){
  int idx = blockIdx.x * 256 + threadIdx.x;
  if (idx >= BATCH * 128 * 9) return;
  int j = idx % 3; int t = idx / 3;
  int i = t % 3;   t /= 3;
  int c = t % 128; int n = t / 128;
  int hs = (i * 26) / 3, he = ((i + 1) * 26 + 2) / 3;
  int ws = (j * 26) / 3, we = ((j + 1) * 26 + 2) / 3;
  const float* p = in + (size_t)n * 729 * 128 + c;
  float s = 0.f;
  for (int r = hs; r < he; ++r)
    for (int cc = ws; cc < we; ++cc){
      const float* q0 = p + (r * 27 + cc) * 128;
      const float* q1 = q0 + 27 * 128;
      float m = fmaxf(fmaxf(q0[0], q0[128]), fmaxf(q1[0], q1[128]));
      s += m;
    }
  flat[(size_t)n * 1152 + c * 9 + i * 3 + j] = s / (float)((he - hs) * (we - ws));
}

// ---------------- final gated combine ----------------
__global__ __launch_bounds__(256) void comb_k(const float* __restrict__ h3,
                                              const float* __restrict__ comb,
                                              float* __restrict__ out){
  int idx = blockIdx.x * 256 + threadIdx.x;
  if (idx >= BATCH * 512) return;
  int o = idx % 512, b = idx / 512;
  float s = 0.f;
  #pragma unroll
  for (int e = 0; e < 3; ++e)
    s += comb[b * 3 + e] * h3[((size_t)e * BATCH + b) * 512 + o];
  out[idx] = s;
}

// ============================================================================
extern "C" void kernel_launch(void* const* d_in, const int* in_sizes, int n_in,
                              void* d_out, int out_size, void* d_ws, size_t ws_size,
                              hipStream_t stream){
  const float* x    = (const float*)d_in[0];
  const float* tw1  = (const float*)d_in[1];  const float* tb1 = (const float*)d_in[2];
  const float* tw2  = (const float*)d_in[3];  const float* tb2 = (const float*)d_in[4];
  const float* tw3  = (const float*)d_in[5];  const float* tb3 = (const float*)d_in[6];
  const float* tw4  = (const float*)d_in[7];  const float* tb4 = (const float*)d_in[8];
  const float* sw1  = (const float*)d_in[9];  const float* sb1 = (const float*)d_in[10];
  const float* bn1g = (const float*)d_in[11]; const float* bn1b = (const float*)d_in[12];
  const float* bn1m = (const float*)d_in[13]; const float* bn1v = (const float*)d_in[14];
  const float* sw2  = (const float*)d_in[15]; const float* sb2 = (const float*)d_in[16];
  const float* bn2g = (const float*)d_in[17]; const float* bn2b = (const float*)d_in[18];
  const float* bn2m = (const float*)d_in[19]; const float* bn2v = (const float*)d_in[20];
  const float* cw   = (const float*)d_in[21]; const float* cb  = (const float*)d_in[22];
  const float* ew1  = (const float*)d_in[23]; const float* eb1 = (const float*)d_in[24];
  const float* ew2  = (const float*)d_in[25]; const float* eb2 = (const float*)d_in[26];
  const float* ew3  = (const float*)d_in[27]; const float* eb3 = (const float*)d_in[28];
  float* out = (float*)d_out;

  // ---- workspace layout (floats), ~157 MB ----
  float* ws = (float*)d_ws;
  size_t off = 0;
  float* comb   = ws + off; off += 768;
  float* tw1T   = ws + off; off += 16 * 27;
  float* tw2T   = ws + off; off += 32 * 400;
  float* sw1T   = ws + off; off += 16 * 147;
  float* sw2T   = ws + off; off += 32 * 144;
  float* flat   = ws + off; off += (size_t)BATCH * 1152;
  float* h3     = ws + off; off += (size_t)BATCH * 3 * 512;
  unsigned short* wpk3h = (unsigned short*)(ws + off); off += 9216;
  unsigned short* wpk3l = (unsigned short*)(ws + off); off += 9216;
  unsigned short* wpk4h = (unsigned short*)(ws + off); off += 36864;
  unsigned short* wpk4l = (unsigned short*)(ws + off); off += 36864;
  off += 16;                                                      // guard pad
  float* bufA   = ws + off; off += 13778944;
  off += 16;                                                      // guard pad
  float* bufB   = ws + off; off += 23887872;
  off += 16;
  (void)ws_size; (void)in_sizes; (void)n_in; (void)out_size;

  // conv-phase aliases in bufA/bufB (lifetimes disjoint, stream-ordered)
  unsigned short* C3h = (unsigned short*)bufA;                 // conv3 out hi/lo
  unsigned short* C3l = C3h + (size_t)13778944;
  unsigned short* P2h = (unsigned short*)bufB;                 // pool2 out hi/lo
  unsigned short* P2l = P2h + (size_t)6889472;

  // head-phase aliases in bufB (valid after papooln_k)
  unsigned short* ub = (unsigned short*)bufB;
  size_t uo = 0;
  unsigned short* ewp1h = ub + uo; uo += 3538944;
  unsigned short* ewp1l = ub + uo; uo += 3538944;
  unsigned short* ewp2h = ub + uo; uo += 1572864;
  unsigned short* ewp2l = ub + uo; uo += 1572864;
  unsigned short* ewp3h = ub + uo; uo += 786432;
  unsigned short* ewp3l = ub + uo; uo += 786432;
  unsigned short* fh    = ub + uo; uo += 294912;
  unsigned short* fl    = ub + uo; uo += 294912;
  unsigned short* h1h   = ub + uo; uo += 786432;
  unsigned short* h1l   = ub + uo; uo += 786432;
  unsigned short* h2h   = ub + uo; uo += 393216;
  unsigned short* h2l   = ub + uo; uo += 393216;   // total 14,745,600 us < bufB

  dim3 blk(256);

  // ---- weight prep (conv) ----
  kwT<<<dim3(( 16*27 +255)/256), blk, 0, stream>>>(tw1, tw1T, 16, 27);
  kwT<<<dim3(( 32*400+255)/256), blk, 0, stream>>>(tw2, tw2T, 32, 400);
  kwT<<<dim3(( 16*147+255)/256), blk, 0, stream>>>(sw1, sw1T, 16, 147);
  kwT<<<dim3(( 32*144+255)/256), blk, 0, stream>>>(sw2, sw2T, 32, 144);
  wpack_k<32,64>  <<<dim3(72),  blk, 0, stream>>>(tw3, wpk3h, wpk3l);
  wpack_k<64,128> <<<dim3(288), blk, 0, stream>>>(tw4, wpk4h, wpk4l);

  // ---- scout router ----
  conv_k<3,16,16,7,4,3,224,224,56,56,1><<<dim3(3136,1), blk, 0, stream>>>(
      x, sw1T, sb1, bn1g, bn1b, bn1m, bn1v, bufA);
  conv_k<16,32,16,3,2,1,56,56,28,28,1><<<dim3(784,2), blk, 0, stream>>>(
      bufA, sw2T, sb2, bn2g, bn2b, bn2m, bn2v, bufB);
  gate_k<<<dim3(256), blk, 0, stream>>>(bufB, cw, cb, comb);

  // ---- trunk front ----
  conv_k<3,16,16,3,4,1,224,224,56,56,0><<<dim3(3136,1), blk, 0, stream>>>(
      x, tw1T, tb1, nullptr, nullptr, nullptr, nullptr, bufA);
  pool_k<16,56,56><<<dim3(48400), blk, 0, stream>>>(bufA, bufB);   // ->[B,16,55,55]
  conv_k<16,32,16,5,2,2,55,55,28,28,0><<<dim3(784,2), blk, 0, stream>>>(
      bufB, tw2T, tb2, nullptr, nullptr, nullptr, nullptr, bufA);

  // ---- pool2 -> padded NHWC bf16 hi/lo ----
  hipMemsetAsync(bufB, 0, (size_t)2 * 6889472 * 2, stream);        // P2 borders
  pool2n_k<<<dim3((BATCH*27*27*32 + 255)/256), blk, 0, stream>>>(bufA, P2h, P2l);

  // ---- conv3 (MFMA) -> padded NHWC bf16 hi/lo ----
  hipMemsetAsync(bufA, 0, (size_t)2 * 13778944 * 2, stream);       // C3 borders
  convM_k<32,64,0><<<dim3(BATCH*14), blk, 0, stream>>>(
      P2h, P2l, wpk3h, wpk3l, tb3, C3h, C3l, nullptr);

  // ---- conv4 (MFMA) -> fp32 NHWC [B,27,27,128] in bufB ----
  convM_k<64,128,1><<<dim3(BATCH*14), blk, 0, stream>>>(
      C3h, C3l, wpk4h, wpk4l, tb4, nullptr, nullptr, bufB);

  papooln_k<<<dim3(1152), blk, 0, stream>>>(bufB, flat);

  // ---- MoE head: pack weights + split A, then 3 MFMA GEMMs ----
  wpackG_k<1152><<<dim3(4608,3), blk, 0, stream>>>(ew1, 1024, ewp1h, ewp1l);
  wpackG_k<1024><<<dim3(2048,3), blk, 0, stream>>>(ew2,  512, ewp2h, ewp2l);
  wpackG_k< 512><<<dim3(1024,3), blk, 0, stream>>>(ew3,  512, ewp3h, ewp3l);
  asplit_k<<<dim3(1152), blk, 0, stream>>>(flat, fh, fl, BATCH*1152);

  gemmM_k<1152,1,0><<<dim3(8,16,3), blk, 0, stream>>>(
      fh, fl, 0L, ewp1h, ewp1l, eb1, 1024, h1h, h1l, nullptr);
  gemmM_k<1024,1,0><<<dim3(8,8,3), blk, 0, stream>>>(
      h1h, h1l, 256L*1024, ewp2h, ewp2l, eb2, 512, h2h, h2l, nullptr);
  gemmM_k< 512,0,1><<<dim3(8,8,3), blk, 0, stream>>>(
      h2h, h2l, 256L*512, ewp3h, ewp3l, eb3, 512, nullptr, nullptr, h3);

  comb_k<<<dim3(512), blk, 0, stream>>>(h3, comb, out);
}

// Round 7
// 750.327 us; speedup vs baseline: 3.4961x; 1.3597x over previous
//
#include <hip/hip_runtime.h>

#define DEV static __device__ __forceinline__

constexpr int BATCH = 256;

DEV float leakyf(float x){ return x > 0.f ? x : 0.2f * x; }

typedef short bf16x8 __attribute__((ext_vector_type(8)));
typedef float f32x4 __attribute__((ext_vector_type(4)));

DEV unsigned short f2bf(float v){
  union { float f; unsigned u; } x; x.f = v;
  unsigned r = x.u + 0x7fffu + ((x.u >> 16) & 1u);
  return (unsigned short)(r >> 16);
}
DEV float bf2f(unsigned short b){
  union { unsigned u; float f; } x; x.u = ((unsigned)b) << 16;
  return x.f;
}

// ---------------- weight transpose: w[OC][RED] -> wT[RED][OC] ----------------
__global__ __launch_bounds__(256) void kwT(const float* __restrict__ w,
                                           float* __restrict__ wt, int OC, int RED){
  int i = blockIdx.x * 256 + threadIdx.x;
  if (i >= OC * RED) return;
  int oc = i / RED, r = i % RED;
  wt[r * OC + oc] = w[i];
}

// ------- pack OIHW conv weights into MFMA B-fragment order, bf16 hi/lo ------
template<int IC,int OC>
__global__ __launch_bounds__(256) void wpack_k(const float* __restrict__ w,
    unsigned short* __restrict__ hi, unsigned short* __restrict__ lo){
  constexpr int S = IC/32, F = OC/16;
  int i = blockIdx.x*256 + threadIdx.x;
  if (i >= 9*S*F*512) return;
  int j = i & 7, L = (i >> 3) & 63, rest = i >> 9;
  int f = rest % F; int q2 = rest / F; int s = q2 % S; int t = q2 / S;
  int oc = f*16 + (L & 15), ic = s*32 + (L >> 4)*8 + j;
  float v = w[((size_t)oc*IC + ic)*9 + t];
  unsigned short h = f2bf(v);
  hi[i] = h; lo[i] = f2bf(v - bf2f(h));
}

// ------- pack strided-conv weights (IC=16): kstep = (kh, kw-pair) -----------
// k = (L>>4)*8+j ; kw = 2*kwp + (k>>4) ; ic = k&15 ; oc = f*16+(L&15)
template<int OC,int K>
__global__ __launch_bounds__(256) void wpackS_k(const float* __restrict__ w,
    unsigned short* __restrict__ hi, unsigned short* __restrict__ lo){
  constexpr int F = OC/16, KWP = (K+1)/2;
  int i = blockIdx.x*256 + threadIdx.x;
  if (i >= K*KWP*F*512) return;
  int j = i & 7, L = (i >> 3) & 63, rest = i >> 9;
  int f = rest % F, s = rest / F;
  int kh = s / KWP, kwp = s % KWP;
  int k = (L >> 4)*8 + j;
  int kw = 2*kwp + (k >> 4), ic = k & 15;
  int oc = f*16 + (L & 15);
  float v = (kw < K) ? w[((size_t)(oc*16 + ic)*K + kh)*K + kw] : 0.f;
  unsigned short h = f2bf(v);
  hi[i] = h; lo[i] = f2bf(v - bf2f(h));
}

// ------- pack expert GEMM weights W[e][N][K] into frag order, bf16 hi/lo ----
template<int KTOT>
__global__ __launch_bounds__(256) void wpackG_k(const float* __restrict__ w, int N,
    unsigned short* __restrict__ hi, unsigned short* __restrict__ lo){
  const int NF = N >> 4, KT = KTOT >> 5;
  const int total = NF * KT * 512;
  const int e = blockIdx.y;
  w  += (size_t)e * N * KTOT;
  hi += (size_t)e * total; lo += (size_t)e * total;
  int i = blockIdx.x*256 + threadIdx.x;
  if (i >= total) return;
  int j = i & 7, L = (i >> 3) & 63, rest = i >> 9;
  int nf = rest % NF, t = rest / NF;
  int n = nf*16 + (L & 15), k = t*32 + (L >> 4)*8 + j;
  float v = w[(size_t)n*KTOT + k];
  unsigned short h = f2bf(v);
  hi[i] = h; lo[i] = f2bf(v - bf2f(h));
}

// ------- split fp32 array into bf16 hi/lo ----------------------------------
__global__ __launch_bounds__(256) void asplit_k(const float* __restrict__ in,
    unsigned short* __restrict__ hi, unsigned short* __restrict__ lo, int nelem){
  int i = blockIdx.x*256 + threadIdx.x;
  if (i >= nelem) return;
  float v = in[i];
  unsigned short h = f2bf(v);
  hi[i] = h; lo[i] = f2bf(v - bf2f(h));
}

// ---------------- fused scout1 + conv1 (both read x, stride 4, 224->56) -----
__global__ __launch_bounds__(256) void fused1_k(
    const float* __restrict__ x,
    const float* __restrict__ swT, const float* __restrict__ cwT,
    const float* __restrict__ sb, const float* __restrict__ cb_,
    const float* __restrict__ g, const float* __restrict__ bt,
    const float* __restrict__ mn, const float* __restrict__ vr,
    float* __restrict__ s1out, float* __restrict__ c1out){
  int idx = blockIdx.x * 256 + threadIdx.x;
  if (idx >= BATCH * 3136) return;
  int n = idx / 3136, p = idx % 3136;
  int oh = p / 56, ow = p % 56;

  float as[16], ac[16];
  #pragma unroll
  for (int j = 0; j < 16; ++j){ as[j] = 0.f; ac[j] = 0.f; }

  for (int ic = 0; ic < 3; ++ic){
    const float* xc = x + ((size_t)n*3 + ic) * 50176;
    #pragma unroll
    for (int kh = 0; kh < 7; ++kh){
      int ih = oh*4 - 3 + kh;
      bool rv = (ih >= 0) && (ih < 224);
      const float* xr = xc + (size_t)ih * 224;
      #pragma unroll
      for (int kw = 0; kw < 7; ++kw){
        int iw = ow*4 - 3 + kw;
        float v = (rv && iw >= 0 && iw < 224) ? xr[iw] : 0.f;
        const float* w1 = swT + (ic*49 + kh*7 + kw)*16;
        #pragma unroll
        for (int j = 0; j < 16; ++j) as[j] += v * w1[j];
        if (kh >= 2 && kh <= 4 && kw >= 2 && kw <= 4){
          const float* w2 = cwT + (ic*9 + (kh-2)*3 + (kw-2))*16;
          #pragma unroll
          for (int j = 0; j < 16; ++j) ac[j] += v * w2[j];
        }
      }
    }
  }

  #pragma unroll
  for (int j = 0; j < 16; ++j){
    float vs = as[j] + sb[j];
    float sc = g[j] / sqrtf(vr[j] + 1e-5f);
    vs = fmaxf((vs - mn[j]) * sc + bt[j], 0.f);
    s1out[((size_t)(n*16 + j)*56 + oh)*56 + ow] = vs;
    c1out[((size_t)(n*16 + j)*56 + oh)*56 + ow] = leakyf(ac[j] + cb_[j]);
  }
}

// ---------------- strided (S=2) MFMA conv, IC=16, out 28x28 NHWC fp32 -------
// Block = (n, oh). Stage K rows x 60 cols x 16ic from NCHW fp32 -> LDS bf16
// hi/lo, XOR-swizzled. 4 waves: wid&1 = oc-frag, wid>>1 = ow-half.
// ACT 0: bias+leaky ; ACT 1: bias+BN+relu
template<int OC,int K,int P,int IH,int IW,int ACT>
__global__ __launch_bounds__(256) void convS_k(
    const float* __restrict__ in,
    const unsigned short* __restrict__ Wh, const unsigned short* __restrict__ Wl,
    const float* __restrict__ bias,
    const float* __restrict__ bng, const float* __restrict__ bnb,
    const float* __restrict__ bnm, const float* __restrict__ bnv,
    float* __restrict__ outNHWC){
  constexpr int F = OC/16, KWP = (K+1)/2;
  __shared__ __align__(16) unsigned short Ah[K*60*16];
  __shared__ __align__(16) unsigned short Al[K*60*16];

  const int tid = threadIdx.x;
  const int n = blockIdx.x / 28, oh = blockIdx.x % 28;

  // ---- stage: (r, ic, c) ; consecutive tid -> consecutive c (coalesced) ----
  for (int i = tid; i < K*16*60; i += 256){
    int c = i % 60; int q = i / 60;
    int ic = q & 15, r = q >> 4;
    int ih = 2*oh - P + r, iw = c - P;
    float v = 0.f;
    if (ih >= 0 && ih < IH && iw >= 0 && iw < IW)
      v = in[((size_t)(n*16 + ic)*IH + ih)*IW + iw];
    unsigned short h = f2bf(v);
    unsigned short l = f2bf(v - bf2f(h));
    int byte = ((r*60 + c)*32 + ic*2) ^ (((c>>1)&7) << 4);
    *(unsigned short*)((char*)Ah + byte) = h;
    *(unsigned short*)((char*)Al + byte) = l;
  }
  __syncthreads();

  const int wid = tid >> 6, lane = tid & 63;
  const int fsel = wid & 1, mb = wid >> 1;
  const int ow_l = min(mb*16 + (lane & 15), 27);
  const int ic0b = ((lane >> 4) & 1) * 16;   // byte offset of 8-ic half
  const int kwo  = (lane >> 4) >> 1;         // kw offset within pair

  f32x4 acc = {0.f,0.f,0.f,0.f};
  #pragma unroll
  for (int kh = 0; kh < K; ++kh){
    #pragma unroll
    for (int kwp = 0; kwp < KWP; ++kwp){
      const int kw = 2*kwp + kwo;
      const int c = 2*ow_l + kw;
      int byte = ((kh*60 + c)*32 + ic0b) ^ (((c>>1)&7) << 4);
      bf16x8 ah = *(const bf16x8*)((const char*)Ah + byte);
      bf16x8 al = *(const bf16x8*)((const char*)Al + byte);
      const int s = kh*KWP + kwp;
      const int fb = (s*F + fsel)*512 + lane*8;
      bf16x8 bh = *(const bf16x8*)(Wh + fb);
      bf16x8 bl = *(const bf16x8*)(Wl + fb);
      acc = __builtin_amdgcn_mfma_f32_16x16x32_bf16(ah, bh, acc, 0,0,0);
      acc = __builtin_amdgcn_mfma_f32_16x16x32_bf16(ah, bl, acc, 0,0,0);
      acc = __builtin_amdgcn_mfma_f32_16x16x32_bf16(al, bh, acc, 0,0,0);
    }
  }

  const int oc = fsel*16 + (lane & 15);
  float bv = bias[oc], sc = 1.f, mm = 0.f, bb = 0.f;
  if (ACT == 1){
    sc = bng[oc] * __frsqrt_rn(bnv[oc] + 1e-5f);
    mm = bnm[oc]; bb = bnb[oc];
  }
  #pragma unroll
  for (int r = 0; r < 4; ++r){
    const int ow = mb*16 + (lane >> 4)*4 + r;
    if (ow >= 28) continue;
    float v = acc[r] + bv;
    if (ACT == 1) v = fmaxf((v - mm)*sc + bb, 0.f);
    else          v = leakyf(v);
    outNHWC[(((size_t)n*28 + oh)*28 + ow)*OC + oc] = v;
  }
}

// ---------------- MFMA split-bf16 3x3 s1 p1 conv on 27x27, padded NHWC ------
template<int IC,int OC,int OUTM>
__global__ __launch_bounds__(256) void convM_k(
    const unsigned short* __restrict__ Ahi_g, const unsigned short* __restrict__ Alo_g,
    const unsigned short* __restrict__ Whi, const unsigned short* __restrict__ Wlo,
    const float* __restrict__ bias,
    unsigned short* __restrict__ OutHi, unsigned short* __restrict__ OutLo,
    float* __restrict__ OutF)
{
  constexpr int S = IC/32, FTOT = OC/16, FW = FTOT/2;
  constexpr int ICB = IC*2, ICG = ICB/16;
  __shared__ __align__(16) char Ah[4*34*ICB];
  __shared__ __align__(16) char Al[4*34*ICB];

  const int tid = threadIdx.x;
  const int bx = blockIdx.x;
  const int n = bx / 14, pr = bx % 14;
  const int oh0 = pr * 2;

  const size_t gbase = ((size_t)n*29) * 29 * IC;
  for (int g = tid; g < 4*34*ICG; g += 256){
    int r = g / (34*ICG);
    int rem = g - r*(34*ICG);
    int c = rem / ICG, q = rem - c*ICG;
    int rp = oh0 + r;
    int4 vh = {0,0,0,0}, vl = {0,0,0,0};
    if (rp <= 28 && c < 29){
      size_t e = gbase + ((size_t)rp*29 + c)*IC + q*8;
      vh = *(const int4*)(Ahi_g + e);
      vl = *(const int4*)(Alo_g + e);
    }
    int off = (r*34 + c)*ICB + q*16;
    int swz = off ^ ((c & 7) << 4);
    *(int4*)(Ah + swz) = vh;
    *(int4*)(Al + swz) = vl;
  }
  __syncthreads();

  const int wid = tid >> 6, lane = tid & 63;
  const int rsel = wid & 1, ocq = wid >> 1;
  const int c0 = lane & 15, kg = (lane >> 4) * 16;
  const int colb0 = c0*ICB + kg, colb1 = (16 + c0)*ICB + kg;
  int msk[3];
  #pragma unroll
  for (int kw = 0; kw < 3; ++kw) msk[kw] = ((c0 + kw) & 7) << 4;

  f32x4 acc[2][FW];
  #pragma unroll
  for (int m = 0; m < 2; ++m)
    #pragma unroll
    for (int f = 0; f < FW; ++f) acc[m][f] = (f32x4){0.f,0.f,0.f,0.f};

  #pragma unroll
  for (int kh = 0; kh < 3; ++kh){
    #pragma unroll
    for (int kw = 0; kw < 3; ++kw){
      #pragma unroll
      for (int s = 0; s < S; ++s){
        const int fr0 = (((kh*3 + kw)*S + s)*FTOT + ocq*FW) * 512 + lane*8;
        bf16x8 bh[FW], bl[FW];
        #pragma unroll
        for (int f = 0; f < FW; ++f){
          bh[f] = *(const bf16x8*)(Whi + fr0 + f*512);
          bl[f] = *(const bf16x8*)(Wlo + fr0 + f*512);
        }
        const int base = ((rsel + kh)*34 + kw)*ICB + s*64;
        const int o0 = (base + colb0) ^ msk[kw];
        const int o1 = (base + colb1) ^ msk[kw];
        bf16x8 ah0 = *(const bf16x8*)(Ah + o0);
        bf16x8 al0 = *(const bf16x8*)(Al + o0);
        bf16x8 ah1 = *(const bf16x8*)(Ah + o1);
        bf16x8 al1 = *(const bf16x8*)(Al + o1);
        #pragma unroll
        for (int f = 0; f < FW; ++f){
          acc[0][f] = __builtin_amdgcn_mfma_f32_16x16x32_bf16(ah0, bh[f], acc[0][f], 0,0,0);
          acc[0][f] = __builtin_amdgcn_mfma_f32_16x16x32_bf16(ah0, bl[f], acc[0][f], 0,0,0);
          acc[0][f] = __builtin_amdgcn_mfma_f32_16x16x32_bf16(al0, bh[f], acc[0][f], 0,0,0);
          acc[1][f] = __builtin_amdgcn_mfma_f32_16x16x32_bf16(ah1, bh[f], acc[1][f], 0,0,0);
          acc[1][f] = __builtin_amdgcn_mfma_f32_16x16x32_bf16(ah1, bl[f], acc[1][f], 0,0,0);
          acc[1][f] = __builtin_amdgcn_mfma_f32_16x16x32_bf16(al1, bh[f], acc[1][f], 0,0,0);
        }
      }
    }
  }

  const int orow = oh0 + rsel;
  if (orow >= 27) return;
  #pragma unroll
  for (int f = 0; f < FW; ++f){
    const int oc = (ocq*FW + f)*16 + c0;
    const float bv = bias[oc];
    #pragma unroll
    for (int m = 0; m < 2; ++m){
      #pragma unroll
      for (int r = 0; r < 4; ++r){
        const int ow = m*16 + (lane >> 4)*4 + r;
        if (ow >= 27) continue;
        float v = leakyf(acc[m][f][r] + bv);
        if (OUTM == 0){
          size_t o = (((size_t)n*29 + orow+1)*29 + ow+1)*OC + oc;
          unsigned short h = f2bf(v);
          OutHi[o] = h;
          OutLo[o] = f2bf(v - bf2f(h));
        } else {
          OutF[(((size_t)n*27 + orow)*27 + ow)*OC + oc] = v;
        }
      }
    }
  }
}

// ---------------- split-bf16 MFMA GEMM for MoE head -------------------------
template<int KTOT,int ACT,int OUTM>
__global__ __launch_bounds__(256) void gemmM_k(
    const unsigned short* __restrict__ Ah, const unsigned short* __restrict__ Al,
    long strideA,
    const unsigned short* __restrict__ Wh, const unsigned short* __restrict__ Wl,
    const float* __restrict__ bias, int N,
    unsigned short* __restrict__ OutH, unsigned short* __restrict__ OutL,
    float* __restrict__ OutF){
  const int e = blockIdx.z;
  Ah += (size_t)e * strideA; Al += (size_t)e * strideA;
  const int NF = N >> 4, KT = KTOT >> 5;
  const size_t wb = (size_t)e * NF * KT * 512;
  Wh += wb; Wl += wb;
  const float* bs = bias + (size_t)e * N;
  const size_t ob = (size_t)e * 256 * N;

  const int tid = threadIdx.x, wid = tid >> 6, lane = tid & 63;
  const int mblk = blockIdx.x * 32;
  const int nf = blockIdx.y * 4 + wid;
  const int r0 = mblk + (lane & 15);
  const int kof = (lane >> 4) * 8;

  f32x4 acc0 = {0,0,0,0}, acc1 = {0,0,0,0};
  for (int t = 0; t < KT; ++t){
    const int k = t*32 + kof;
    bf16x8 ah0 = *(const bf16x8*)(Ah + (size_t)r0*KTOT + k);
    bf16x8 al0 = *(const bf16x8*)(Al + (size_t)r0*KTOT + k);
    bf16x8 ah1 = *(const bf16x8*)(Ah + (size_t)(r0+16)*KTOT + k);
    bf16x8 al1 = *(const bf16x8*)(Al + (size_t)(r0+16)*KTOT + k);
    const size_t fb = ((size_t)t*NF + nf)*512 + lane*8;
    bf16x8 bh = *(const bf16x8*)(Wh + fb);
    bf16x8 bl = *(const bf16x8*)(Wl + fb);
    acc0 = __builtin_amdgcn_mfma_f32_16x16x32_bf16(ah0, bh, acc0, 0,0,0);
    acc0 = __builtin_amdgcn_mfma_f32_16x16x32_bf16(ah0, bl, acc0, 0,0,0);
    acc0 = __builtin_amdgcn_mfma_f32_16x16x32_bf16(al0, bh, acc0, 0,0,0);
    acc1 = __builtin_amdgcn_mfma_f32_16x16x32_bf16(ah1, bh, acc1, 0,0,0);
    acc1 = __builtin_amdgcn_mfma_f32_16x16x32_bf16(ah1, bl, acc1, 0,0,0);
    acc1 = __builtin_amdgcn_mfma_f32_16x16x32_bf16(al1, bh, acc1, 0,0,0);
  }
  const int n = nf*16 + (lane & 15);
  const float bv = bs[n];
  #pragma unroll
  for (int mi = 0; mi < 2; ++mi){
    f32x4 a = mi ? acc1 : acc0;
    #pragma unroll
    for (int r = 0; r < 4; ++r){
      const int m = mblk + mi*16 + (lane >> 4)*4 + r;
      float v = a[r] + bv;
      if (ACT == 1) v = leakyf(v);
      const size_t o = ob + (size_t)m*N + n;
      if (OUTM == 0){
        unsigned short h = f2bf(v);
        OutH[o] = h; OutL[o] = f2bf(v - bf2f(h));
      } else {
        OutF[o] = v;
      }
    }
  }
}

// ---------------- 2x2 stride-1 maxpool (NCHW) ----------------
template<int C,int IH,int IW>
__global__ __launch_bounds__(256) void pool_k(const float* __restrict__ in,
                                              float* __restrict__ out){
  constexpr int OH = IH - 1, OW = IW - 1;
  int idx = blockIdx.x * 256 + threadIdx.x;
  if (idx >= BATCH * C * OH * OW) return;
  int ow = idx % OW; int t = idx / OW;
  int oh = t % OH;   t /= OH;
  const float* p = in + ((size_t)t * IH + oh) * IW + ow;
  out[idx] = fmaxf(fmaxf(p[0], p[1]), fmaxf(p[IW], p[IW + 1]));
}

// ------- pool2: NHWC fp32 [B,28,28,32] -> padded NHWC bf16 hi/lo [B,29,29,32]
__global__ __launch_bounds__(256) void pool2n_k(const float* __restrict__ in,
    unsigned short* __restrict__ hi, unsigned short* __restrict__ lo){
  int idx = blockIdx.x*256 + threadIdx.x;
  if (idx >= BATCH*27*27*32) return;
  int ic = idx & 31; int p = idx >> 5;
  int ow = p % 27; int t = p / 27; int oh = t % 27; int n = t / 27;
  const float* b = in + (((size_t)n*28 + oh)*28 + ow)*32 + ic;
  float v = fmaxf(fmaxf(b[0], b[32]), fmaxf(b[28*32], b[29*32]));
  size_t o = (((size_t)n*29 + oh+1)*29 + ow+1)*32 + ic;
  unsigned short h = f2bf(v);
  hi[o] = h; lo[o] = f2bf(v - bf2f(h));
}

// ---------------- scout gate (NHWC input [B,28,28,32]) ----------------
__global__ __launch_bounds__(256) void gate_k(const float* __restrict__ s2,
                                              const float* __restrict__ cw,
                                              const float* __restrict__ cb,
                                              float* __restrict__ comb){
  int n = blockIdx.x;
  int tid = threadIdx.x;
  int c = tid & 31;     // channel
  int sub = tid >> 5;   // 0..7
  const float* p = s2 + (size_t)n * 784 * 32 + c;
  float s = 0.f;
  for (int i = sub * 98; i < sub * 98 + 98; ++i) s += p[(size_t)i * 32];
  __shared__ float red[32][8];
  red[c][sub] = s;
  __syncthreads();
  if (tid < 32){
    float tot = 0.f;
    #pragma unroll
    for (int k = 0; k < 8; ++k) tot += red[tid][k];
    red[tid][0] = tot / 784.f;
  }
  __syncthreads();
  if (tid == 0){
    float lg[3];
    for (int e = 0; e < 3; ++e){
      float a = cb[e];
      for (int c2 = 0; c2 < 32; ++c2) a += red[c2][0] * cw[e * 32 + c2];
      lg[e] = a;
    }
    float m = fmaxf(lg[0], fmaxf(lg[1], lg[2]));
    float ex[3], sum = 0.f;
    for (int e = 0; e < 3; ++e){ ex[e] = expf(lg[e] - m); sum += ex[e]; }
    float pr[3];
    for (int e = 0; e < 3; ++e) pr[e] = ex[e] / sum;
    int i1 = 0;
    if (pr[1] > pr[0]) i1 = 1;
    if (pr[2] > pr[i1]) i1 = 2;
    int i2 = -1;
    for (int e = 0; e < 3; ++e){
      if (e == i1) continue;
      if (i2 < 0 || pr[e] > pr[i2]) i2 = e;
    }
    float s12 = pr[i1] + pr[i2] + 1e-6f;
    float cmb[3] = {0.f, 0.f, 0.f};
    cmb[i1] = pr[i1] / s12;
    cmb[i2] = pr[i2] / s12;
    comb[n * 3 + 0] = cmb[0];
    comb[n * 3 + 1] = cmb[1];
    comb[n * 3 + 2] = cmb[2];
  }
}

// ------ fused maxpool2s1(27->26) + adaptive avg(26->3), NHWC input ----------
__global__ __launch_bounds__(256) void papooln_k(const float* __restrict__ in,
                                                 float* __restrict__ flat){
  int idx = blockIdx.x * 256 + threadIdx.x;
  if (idx >= BATCH * 128 * 9) return;
  int j = idx % 3; int t = idx / 3;
  int i = t % 3;   t /= 3;
  int c = t % 128; int n = t / 128;
  int hs = (i * 26) / 3, he = ((i + 1) * 26 + 2) / 3;
  int ws = (j * 26) / 3, we = ((j + 1) * 26 + 2) / 3;
  const float* p = in + (size_t)n * 729 * 128 + c;
  float s = 0.f;
  for (int r = hs; r < he; ++r)
    for (int cc = ws; cc < we; ++cc){
      const float* q0 = p + (r * 27 + cc) * 128;
      const float* q1 = q0 + 27 * 128;
      float m = fmaxf(fmaxf(q0[0], q0[128]), fmaxf(q1[0], q1[128]));
      s += m;
    }
  flat[(size_t)n * 1152 + c * 9 + i * 3 + j] = s / (float)((he - hs) * (we - ws));
}

// ---------------- final gated combine ----------------
__global__ __launch_bounds__(256) void comb_k(const float* __restrict__ h3,
                                              const float* __restrict__ comb,
                                              float* __restrict__ out){
  int idx = blockIdx.x * 256 + threadIdx.x;
  if (idx >= BATCH * 512) return;
  int o = idx % 512, b = idx / 512;
  float s = 0.f;
  #pragma unroll
  for (int e = 0; e < 3; ++e)
    s += comb[b * 3 + e] * h3[((size_t)e * BATCH + b) * 512 + o];
  out[idx] = s;
}

// ============================================================================
extern "C" void kernel_launch(void* const* d_in, const int* in_sizes, int n_in,
                              void* d_out, int out_size, void* d_ws, size_t ws_size,
                              hipStream_t stream){
  const float* x    = (const float*)d_in[0];
  const float* tw1  = (const float*)d_in[1];  const float* tb1 = (const float*)d_in[2];
  const float* tw2  = (const float*)d_in[3];  const float* tb2 = (const float*)d_in[4];
  const float* tw3  = (const float*)d_in[5];  const float* tb3 = (const float*)d_in[6];
  const float* tw4  = (const float*)d_in[7];  const float* tb4 = (const float*)d_in[8];
  const float* sw1  = (const float*)d_in[9];  const float* sb1 = (const float*)d_in[10];
  const float* bn1g = (const float*)d_in[11]; const float* bn1b = (const float*)d_in[12];
  const float* bn1m = (const float*)d_in[13]; const float* bn1v = (const float*)d_in[14];
  const float* sw2  = (const float*)d_in[15]; const float* sb2 = (const float*)d_in[16];
  const float* bn2g = (const float*)d_in[17]; const float* bn2b = (const float*)d_in[18];
  const float* bn2m = (const float*)d_in[19]; const float* bn2v = (const float*)d_in[20];
  const float* cw   = (const float*)d_in[21]; const float* cb  = (const float*)d_in[22];
  const float* ew1  = (const float*)d_in[23]; const float* eb1 = (const float*)d_in[24];
  const float* ew2  = (const float*)d_in[25]; const float* eb2 = (const float*)d_in[26];
  const float* ew3  = (const float*)d_in[27]; const float* eb3 = (const float*)d_in[28];
  float* out = (float*)d_out;

  // ---- workspace layout (floats), ~157 MB ----
  float* ws = (float*)d_ws;
  size_t off = 0;
  float* comb   = ws + off; off += 768;
  float* tw1T   = ws + off; off += 16 * 27;
  float* sw1T   = ws + off; off += 16 * 147;
  float* flat   = ws + off; off += (size_t)BATCH * 1152;
  float* h3     = ws + off; off += (size_t)BATCH * 3 * 512;
  unsigned short* wpk3h = (unsigned short*)(ws + off); off += 9216;
  unsigned short* wpk3l = (unsigned short*)(ws + off); off += 9216;
  unsigned short* wpk4h = (unsigned short*)(ws + off); off += 36864;
  unsigned short* wpk4l = (unsigned short*)(ws + off); off += 36864;
  unsigned short* wp2h  = (unsigned short*)(ws + off); off += 7680;  // conv2 K5: 15360 us
  unsigned short* wp2l  = (unsigned short*)(ws + off); off += 7680;
  unsigned short* wps2h = (unsigned short*)(ws + off); off += 3072;  // scout2 K3: 6144 us
  unsigned short* wps2l = (unsigned short*)(ws + off); off += 3072;
  off += 16;                                                      // guard pad
  float* bufA   = ws + off; off += 13778944;
  off += 16;                                                      // guard pad
  float* bufB   = ws + off; off += 23887872;
  off += 16;
  (void)ws_size; (void)in_sizes; (void)n_in; (void)out_size;

  // phase aliases (lifetimes disjoint, single-stream ordered)
  float* s1out = bufA;                       // [B,16,56,56] NCHW
  float* c1out = bufB;                       // [B,16,56,56] NCHW
  float* s2out = bufB + 16000000;            // [B,28,28,32] NHWC, 6,422,528 f
  float* p1out = bufA;                       // [B,16,55,55] NCHW (after gate... after scout2)
  float* c2out = bufB;                       // [B,28,28,32] NHWC
  unsigned short* P2h = (unsigned short*)(bufB + 8000000);
  unsigned short* P2l = P2h + (size_t)6889472;
  unsigned short* C3h = (unsigned short*)bufA;
  unsigned short* C3l = C3h + (size_t)13778944;
  float* c4out = bufB;                       // [B,27,27,128] NHWC

  // head-phase aliases in bufB (valid after papooln_k)
  unsigned short* ub = (unsigned short*)bufB;
  size_t uo = 0;
  unsigned short* ewp1h = ub + uo; uo += 3538944;
  unsigned short* ewp1l = ub + uo; uo += 3538944;
  unsigned short* ewp2h = ub + uo; uo += 1572864;
  unsigned short* ewp2l = ub + uo; uo += 1572864;
  unsigned short* ewp3h = ub + uo; uo += 786432;
  unsigned short* ewp3l = ub + uo; uo += 786432;
  unsigned short* fh    = ub + uo; uo += 294912;
  unsigned short* fl    = ub + uo; uo += 294912;
  unsigned short* h1h   = ub + uo; uo += 786432;
  unsigned short* h1l   = ub + uo; uo += 786432;
  unsigned short* h2h   = ub + uo; uo += 393216;
  unsigned short* h2l   = ub + uo; uo += 393216;

  dim3 blk(256);

  // ---- weight prep ----
  kwT<<<dim3(( 16*27 +255)/256), blk, 0, stream>>>(tw1, tw1T, 16, 27);
  kwT<<<dim3(( 16*147+255)/256), blk, 0, stream>>>(sw1, sw1T, 16, 147);
  wpack_k<32,64>  <<<dim3(72),  blk, 0, stream>>>(tw3, wpk3h, wpk3l);
  wpack_k<64,128> <<<dim3(288), blk, 0, stream>>>(tw4, wpk4h, wpk4l);
  wpackS_k<32,5><<<dim3(60), blk, 0, stream>>>(tw2, wp2h, wp2l);
  wpackS_k<32,3><<<dim3(24), blk, 0, stream>>>(sw2, wps2h, wps2l);

  // ---- fused scout1 + conv1 (one pass over x) ----
  fused1_k<<<dim3(3136), blk, 0, stream>>>(
      x, sw1T, tw1T, sb1, tb1, bn1g, bn1b, bn1m, bn1v, s1out, c1out);

  // ---- scout2 (MFMA strided) + gate ----
  convS_k<32,3,1,56,56,1><<<dim3(BATCH*28), blk, 0, stream>>>(
      s1out, wps2h, wps2l, sb2, bn2g, bn2b, bn2m, bn2v, s2out);
  gate_k<<<dim3(256), blk, 0, stream>>>(s2out, cw, cb, comb);

  // ---- pool1 -> conv2 (MFMA strided) ----
  pool_k<16,56,56><<<dim3(48400), blk, 0, stream>>>(c1out, p1out);
  convS_k<32,5,2,55,55,0><<<dim3(BATCH*28), blk, 0, stream>>>(
      p1out, wp2h, wp2l, tb2, nullptr, nullptr, nullptr, nullptr, c2out);

  // ---- pool2 -> padded NHWC bf16 hi/lo ----
  hipMemsetAsync(bufB + 8000000, 0, (size_t)2 * 6889472 * 2, stream);
  pool2n_k<<<dim3((BATCH*27*27*32 + 255)/256), blk, 0, stream>>>(c2out, P2h, P2l);

  // ---- conv3 (MFMA) -> padded NHWC bf16 hi/lo ----
  hipMemsetAsync(bufA, 0, (size_t)2 * 13778944 * 2, stream);
  convM_k<32,64,0><<<dim3(BATCH*14), blk, 0, stream>>>(
      P2h, P2l, wpk3h, wpk3l, tb3, C3h, C3l, nullptr);

  // ---- conv4 (MFMA) -> fp32 NHWC [B,27,27,128] ----
  convM_k<64,128,1><<<dim3(BATCH*14), blk, 0, stream>>>(
      C3h, C3l, wpk4h, wpk4l, tb4, nullptr, nullptr, c4out);

  papooln_k<<<dim3(1152), blk, 0, stream>>>(c4out, flat);

  // ---- MoE head: pack weights + split A, then 3 MFMA GEMMs ----
  wpackG_k<1152><<<dim3(4608,3), blk, 0, stream>>>(ew1, 1024, ewp1h, ewp1l);
  wpackG_k<1024><<<dim3(2048,3), blk, 0, stream>>>(ew2,  512, ewp2h, ewp2l);
  wpackG_k< 512><<<dim3(1024,3), blk, 0, stream>>>(ew3,  512, ewp3h, ewp3l);
  asplit_k<<<dim3(1152), blk, 0, stream>>>(flat, fh, fl, BATCH*1152);

  gemmM_k<1152,1,0><<<dim3(8,16,3), blk, 0, stream>>>(
      fh, fl, 0L, ewp1h, ewp1l, eb1, 1024, h1h, h1l, nullptr);
  gemmM_k<1024,1,0><<<dim3(8,8,3), blk, 0, stream>>>(
      h1h, h1l, 256L*1024, ewp2h, ewp2l, eb2, 512, h2h, h2l, nullptr);
  gemmM_k< 512,0,1><<<dim3(8,8,3), blk, 0, stream>>>(
      h2h, h2l, 256L*512, ewp3h, ewp3l, eb3, 512, nullptr, nullptr, h3);

  comb_k<<<dim3(512), blk, 0, stream>>>(h3, comb, out);
}

// Round 8
// 651.636 us; speedup vs baseline: 4.0256x; 1.1515x over previous
//
#include <hip/hip_runtime.h>

#define DEV static __device__ __forceinline__

constexpr int BATCH = 256;

DEV float leakyf(float x){ return x > 0.f ? x : 0.2f * x; }

typedef short bf16x8 __attribute__((ext_vector_type(8)));
typedef float f32x4 __attribute__((ext_vector_type(4)));

DEV unsigned short f2bf(float v){
  union { float f; unsigned u; } x; x.f = v;
  unsigned r = x.u + 0x7fffu + ((x.u >> 16) & 1u);
  return (unsigned short)(r >> 16);
}
DEV float bf2f(unsigned short b){
  union { unsigned u; float f; } x; x.u = ((unsigned)b) << 16;
  return x.f;
}

// ------- pack OIHW conv weights into MFMA B-fragment order, bf16 hi/lo ------
template<int IC,int OC>
__global__ __launch_bounds__(256) void wpack_k(const float* __restrict__ w,
    unsigned short* __restrict__ hi, unsigned short* __restrict__ lo){
  constexpr int S = IC/32, F = OC/16;
  int i = blockIdx.x*256 + threadIdx.x;
  if (i >= 9*S*F*512) return;
  int j = i & 7, L = (i >> 3) & 63, rest = i >> 9;
  int f = rest % F; int q2 = rest / F; int s = q2 % S; int t = q2 / S;
  int oc = f*16 + (L & 15), ic = s*32 + (L >> 4)*8 + j;
  float v = w[((size_t)oc*IC + ic)*9 + t];
  unsigned short h = f2bf(v);
  hi[i] = h; lo[i] = f2bf(v - bf2f(h));
}

// ------- pack strided-conv weights (IC=16): kstep = (kh, kw-pair) -----------
template<int OC,int K>
__global__ __launch_bounds__(256) void wpackS_k(const float* __restrict__ w,
    unsigned short* __restrict__ hi, unsigned short* __restrict__ lo){
  constexpr int F = OC/16, KWP = (K+1)/2;
  int i = blockIdx.x*256 + threadIdx.x;
  if (i >= K*KWP*F*512) return;
  int j = i & 7, L = (i >> 3) & 63, rest = i >> 9;
  int f = rest % F, s = rest / F;
  int kh = s / KWP, kwp = s % KWP;
  int k = (L >> 4)*8 + j;
  int kw = 2*kwp + (k >> 4), ic = k & 15;
  int oc = f*16 + (L & 15);
  float v = (kw < K) ? w[((size_t)(oc*16 + ic)*K + kh)*K + kw] : 0.f;
  unsigned short h = f2bf(v);
  hi[i] = h; lo[i] = f2bf(v - bf2f(h));
}

// ------- pack scout1(k7) + conv1(k3) weights into space-to-depth frag order -
// k = tap*48 + (ph_r*4+ph_c)*3 + ic ; tap t: dr=(t>>1)-1, dc=(t&1)-1
// nf 0 = scout oc (pad 3), nf 1 = conv1 oc (pad 1)
__global__ __launch_bounds__(256) void wpackF_k(const float* __restrict__ sw1,
    const float* __restrict__ tw1,
    unsigned short* __restrict__ hi, unsigned short* __restrict__ lo){
  int i = blockIdx.x*256 + threadIdx.x;
  if (i >= 6*2*512) return;
  int j = i & 7, L = (i >> 3) & 63, rest = i >> 9;
  int nf = rest & 1, s = rest >> 1;
  int k = s*32 + (L >> 4)*8 + j;
  int oc = L & 15;
  int t = k / 48, c = k % 48;
  int dr = (t >> 1) - 1, dc = (t & 1) - 1;
  int pr = c / 12, pc = (c % 12) / 3, ic = c % 3;
  float v = 0.f;
  if (nf == 0){
    int kh = 4*dr + pr + 3, kw = 4*dc + pc + 3;
    if (kh >= 0 && kh < 7 && kw >= 0 && kw < 7) v = sw1[((oc*3 + ic)*7 + kh)*7 + kw];
  } else {
    int kh = 4*dr + pr + 1, kw = 4*dc + pc + 1;
    if (kh >= 0 && kh < 3 && kw >= 0 && kw < 3) v = tw1[((oc*3 + ic)*3 + kh)*3 + kw];
  }
  unsigned short h = f2bf(v);
  hi[i] = h; lo[i] = f2bf(v - bf2f(h));
}

// ------- pack expert GEMM weights W[e][N][K] into frag order, bf16 hi/lo ----
template<int KTOT>
__global__ __launch_bounds__(256) void wpackG_k(const float* __restrict__ w, int N,
    unsigned short* __restrict__ hi, unsigned short* __restrict__ lo){
  const int NF = N >> 4, KT = KTOT >> 5;
  const int total = NF * KT * 512;
  const int e = blockIdx.y;
  w  += (size_t)e * N * KTOT;
  hi += (size_t)e * total; lo += (size_t)e * total;
  int i = blockIdx.x*256 + threadIdx.x;
  if (i >= total) return;
  int j = i & 7, L = (i >> 3) & 63, rest = i >> 9;
  int nf = rest % NF, t = rest / NF;
  int n = nf*16 + (L & 15), k = t*32 + (L >> 4)*8 + j;
  float v = w[(size_t)n*KTOT + k];
  unsigned short h = f2bf(v);
  hi[i] = h; lo[i] = f2bf(v - bf2f(h));
}

// ------- split fp32 array into bf16 hi/lo ----------------------------------
__global__ __launch_bounds__(256) void asplit_k(const float* __restrict__ in,
    unsigned short* __restrict__ hi, unsigned short* __restrict__ lo, int nelem){
  int i = blockIdx.x*256 + threadIdx.x;
  if (i >= nelem) return;
  float v = in[i];
  unsigned short h = f2bf(v);
  hi[i] = h; lo[i] = f2bf(v - bf2f(h));
}

// ---------- fused scout1+conv1 via space-to-depth MFMA (stride4 -> 2x2 s1) --
// Block = (n, 2 output rows). LDS: P[3 rows][58 cols][48ch +8 pad] bf16 hi/lo.
// 4 waves x {2 m-frags, 2 n-frags (scout oc | conv1 oc)}, K = 192 (6 steps).
__global__ __launch_bounds__(256) void fusedM_k(
    const float* __restrict__ x,
    const unsigned short* __restrict__ Wh, const unsigned short* __restrict__ Wl,
    const float* __restrict__ sb, const float* __restrict__ cb_,
    const float* __restrict__ g, const float* __restrict__ bt,
    const float* __restrict__ mn, const float* __restrict__ vr,
    float* __restrict__ s1out, float* __restrict__ c1out){
  __shared__ __align__(16) unsigned short Ah[3*58*56];
  __shared__ __align__(16) unsigned short Al[3*58*56];
  const int tid = threadIdx.x;
  const int n = blockIdx.x / 28, oh0 = (blockIdx.x % 28) * 2;

  { // zero both LDS tiles (covers OOB rows, col 0, pad channels)
    int4* a = (int4*)Ah; int4* b = (int4*)Al;
    for (int i = tid; i < 1218; i += 256){
      a[i] = (int4){0,0,0,0}; b[i] = (int4){0,0,0,0};
    }
  }
  __syncthreads();

  // stage 12 x-rows x 3 ic x 224 cols (coalesced float4), space-to-depth
  for (int i = tid; i < 2016; i += 256){
    int m = i % 56; int rc = i / 56;
    int ic = rc % 3, ridx = rc / 3;
    int ih = 4*oh0 - 4 + ridx;
    if (ih < 0 || ih >= 224) continue;
    float4 v = *(const float4*)(x + ((size_t)(n*3 + ic)*224 + ih)*224 + 4*m);
    int rr = ridx >> 2, pr = ridx & 3, cc = m + 1;
    int base = (rr*58 + cc)*56 + pr*12 + ic;
    float vv[4] = {v.x, v.y, v.z, v.w};
    #pragma unroll
    for (int q = 0; q < 4; ++q){
      unsigned short h = f2bf(vv[q]);
      Ah[base + q*3] = h;
      Al[base + q*3] = f2bf(vv[q] - bf2f(h));
    }
  }
  __syncthreads();

  const int wid = tid >> 6, lane = tid & 63;
  const int kg8 = (lane >> 4) * 8;
  f32x4 acc[2][2];
  #pragma unroll
  for (int mi = 0; mi < 2; ++mi)
    #pragma unroll
    for (int nf = 0; nf < 2; ++nf) acc[mi][nf] = (f32x4){0.f,0.f,0.f,0.f};

  #pragma unroll
  for (int s = 0; s < 6; ++s){
    const int kk = s*32 + kg8;
    const int t = kk / 48, c0 = kk - t*48;
    const int ra = t >> 1, ca = t & 1;
    bf16x8 ah[2], al[2];
    #pragma unroll
    for (int mi = 0; mi < 2; ++mi){
      const int m = 2*wid + mi;
      const int rowsel = m >> 2;
      const int ow = (m & 3)*16 + (lane & 15);
      const int owc = ow > 55 ? 55 : ow;
      const int idx = ((rowsel + ra)*58 + owc + ca)*56 + c0;
      ah[mi] = *(const bf16x8*)(Ah + idx);
      al[mi] = *(const bf16x8*)(Al + idx);
    }
    #pragma unroll
    for (int nf = 0; nf < 2; ++nf){
      const int fb = (s*2 + nf)*512 + lane*8;
      bf16x8 bh = *(const bf16x8*)(Wh + fb);
      bf16x8 bl = *(const bf16x8*)(Wl + fb);
      #pragma unroll
      for (int mi = 0; mi < 2; ++mi){
        acc[mi][nf] = __builtin_amdgcn_mfma_f32_16x16x32_bf16(ah[mi], bh, acc[mi][nf], 0,0,0);
        acc[mi][nf] = __builtin_amdgcn_mfma_f32_16x16x32_bf16(ah[mi], bl, acc[mi][nf], 0,0,0);
        acc[mi][nf] = __builtin_amdgcn_mfma_f32_16x16x32_bf16(al[mi], bh, acc[mi][nf], 0,0,0);
      }
    }
  }

  const int oc = lane & 15;
  const float sbv = sb[oc];
  const float scv = g[oc] * __frsqrt_rn(vr[oc] + 1e-5f);
  const float mnv = mn[oc], btv = bt[oc], cbv = cb_[oc];
  #pragma unroll
  for (int mi = 0; mi < 2; ++mi){
    const int m = 2*wid + mi;
    const int row = oh0 + (m >> 2);
    const int owb = (m & 3)*16 + (lane >> 4)*4;
    #pragma unroll
    for (int r = 0; r < 4; ++r){
      const int ow = owb + r;
      if (ow >= 56) continue;
      float vs = acc[mi][0][r] + sbv;
      vs = fmaxf((vs - mnv)*scv + btv, 0.f);
      s1out[((size_t)(n*16 + oc)*56 + row)*56 + ow] = vs;
      c1out[((size_t)(n*16 + oc)*56 + row)*56 + ow] = leakyf(acc[mi][1][r] + cbv);
    }
  }
}

// ---------------- strided (S=2) MFMA conv, IC=16, out 28x28 NHWC fp32 -------
template<int OC,int K,int P,int IH,int IW,int ACT>
__global__ __launch_bounds__(256) void convS_k(
    const float* __restrict__ in,
    const unsigned short* __restrict__ Wh, const unsigned short* __restrict__ Wl,
    const float* __restrict__ bias,
    const float* __restrict__ bng, const float* __restrict__ bnb,
    const float* __restrict__ bnm, const float* __restrict__ bnv,
    float* __restrict__ outNHWC){
  constexpr int F = OC/16, KWP = (K+1)/2;
  __shared__ __align__(16) unsigned short Ah[K*60*16];
  __shared__ __align__(16) unsigned short Al[K*60*16];

  const int tid = threadIdx.x;
  const int n = blockIdx.x / 28, oh = blockIdx.x % 28;

  for (int i = tid; i < K*16*60; i += 256){
    int c = i % 60; int q = i / 60;
    int ic = q & 15, r = q >> 4;
    int ih = 2*oh - P + r, iw = c - P;
    float v = 0.f;
    if (ih >= 0 && ih < IH && iw >= 0 && iw < IW)
      v = in[((size_t)(n*16 + ic)*IH + ih)*IW + iw];
    unsigned short h = f2bf(v);
    unsigned short l = f2bf(v - bf2f(h));
    int byte = ((r*60 + c)*32 + ic*2) ^ (((c>>1)&7) << 4);
    *(unsigned short*)((char*)Ah + byte) = h;
    *(unsigned short*)((char*)Al + byte) = l;
  }
  __syncthreads();

  const int wid = tid >> 6, lane = tid & 63;
  const int fsel = wid & 1, mb = wid >> 1;
  const int ow_l = min(mb*16 + (lane & 15), 27);
  const int ic0b = ((lane >> 4) & 1) * 16;
  const int kwo  = (lane >> 4) >> 1;

  f32x4 acc = {0.f,0.f,0.f,0.f};
  #pragma unroll
  for (int kh = 0; kh < K; ++kh){
    #pragma unroll
    for (int kwp = 0; kwp < KWP; ++kwp){
      const int kw = 2*kwp + kwo;
      const int c = 2*ow_l + kw;
      int byte = ((kh*60 + c)*32 + ic0b) ^ (((c>>1)&7) << 4);
      bf16x8 ah = *(const bf16x8*)((const char*)Ah + byte);
      bf16x8 al = *(const bf16x8*)((const char*)Al + byte);
      const int s = kh*KWP + kwp;
      const int fb = (s*F + fsel)*512 + lane*8;
      bf16x8 bh = *(const bf16x8*)(Wh + fb);
      bf16x8 bl = *(const bf16x8*)(Wl + fb);
      acc = __builtin_amdgcn_mfma_f32_16x16x32_bf16(ah, bh, acc, 0,0,0);
      acc = __builtin_amdgcn_mfma_f32_16x16x32_bf16(ah, bl, acc, 0,0,0);
      acc = __builtin_amdgcn_mfma_f32_16x16x32_bf16(al, bh, acc, 0,0,0);
    }
  }

  const int oc = fsel*16 + (lane & 15);
  float bv = bias[oc], sc = 1.f, mm = 0.f, bb = 0.f;
  if (ACT == 1){
    sc = bng[oc] * __frsqrt_rn(bnv[oc] + 1e-5f);
    mm = bnm[oc]; bb = bnb[oc];
  }
  #pragma unroll
  for (int r = 0; r < 4; ++r){
    const int ow = mb*16 + (lane >> 4)*4 + r;
    if (ow >= 28) continue;
    float v = acc[r] + bv;
    if (ACT == 1) v = fmaxf((v - mm)*sc + bb, 0.f);
    else          v = leakyf(v);
    outNHWC[(((size_t)n*28 + oh)*28 + ow)*OC + oc] = v;
  }
}

// ---------------- MFMA split-bf16 3x3 s1 p1 conv on 27x27, padded NHWC ------
template<int IC,int OC,int OUTM>
__global__ __launch_bounds__(256) void convM_k(
    const unsigned short* __restrict__ Ahi_g, const unsigned short* __restrict__ Alo_g,
    const unsigned short* __restrict__ Whi, const unsigned short* __restrict__ Wlo,
    const float* __restrict__ bias,
    unsigned short* __restrict__ OutHi, unsigned short* __restrict__ OutLo,
    float* __restrict__ OutF)
{
  constexpr int S = IC/32, FTOT = OC/16, FW = FTOT/2;
  constexpr int ICB = IC*2, ICG = ICB/16;
  __shared__ __align__(16) char Ah[4*34*ICB];
  __shared__ __align__(16) char Al[4*34*ICB];

  const int tid = threadIdx.x;
  const int bx = blockIdx.x;
  const int n = bx / 14, pr = bx % 14;
  const int oh0 = pr * 2;

  const size_t gbase = ((size_t)n*29) * 29 * IC;
  for (int g = tid; g < 4*34*ICG; g += 256){
    int r = g / (34*ICG);
    int rem = g - r*(34*ICG);
    int c = rem / ICG, q = rem - c*ICG;
    int rp = oh0 + r;
    int4 vh = {0,0,0,0}, vl = {0,0,0,0};
    if (rp <= 28 && c < 29){
      size_t e = gbase + ((size_t)rp*29 + c)*IC + q*8;
      vh = *(const int4*)(Ahi_g + e);
      vl = *(const int4*)(Alo_g + e);
    }
    int off = (r*34 + c)*ICB + q*16;
    int swz = off ^ ((c & 7) << 4);
    *(int4*)(Ah + swz) = vh;
    *(int4*)(Al + swz) = vl;
  }
  __syncthreads();

  const int wid = tid >> 6, lane = tid & 63;
  const int rsel = wid & 1, ocq = wid >> 1;
  const int c0 = lane & 15, kg = (lane >> 4) * 16;
  const int colb0 = c0*ICB + kg, colb1 = (16 + c0)*ICB + kg;
  int msk[3];
  #pragma unroll
  for (int kw = 0; kw < 3; ++kw) msk[kw] = ((c0 + kw) & 7) << 4;

  f32x4 acc[2][FW];
  #pragma unroll
  for (int m = 0; m < 2; ++m)
    #pragma unroll
    for (int f = 0; f < FW; ++f) acc[m][f] = (f32x4){0.f,0.f,0.f,0.f};

  #pragma unroll
  for (int kh = 0; kh < 3; ++kh){
    #pragma unroll
    for (int kw = 0; kw < 3; ++kw){
      #pragma unroll
      for (int s = 0; s < S; ++s){
        const int fr0 = (((kh*3 + kw)*S + s)*FTOT + ocq*FW) * 512 + lane*8;
        bf16x8 bh[FW], bl[FW];
        #pragma unroll
        for (int f = 0; f < FW; ++f){
          bh[f] = *(const bf16x8*)(Whi + fr0 + f*512);
          bl[f] = *(const bf16x8*)(Wlo + fr0 + f*512);
        }
        const int base = ((rsel + kh)*34 + kw)*ICB + s*64;
        const int o0 = (base + colb0) ^ msk[kw];
        const int o1 = (base + colb1) ^ msk[kw];
        bf16x8 ah0 = *(const bf16x8*)(Ah + o0);
        bf16x8 al0 = *(const bf16x8*)(Al + o0);
        bf16x8 ah1 = *(const bf16x8*)(Ah + o1);
        bf16x8 al1 = *(const bf16x8*)(Al + o1);
        #pragma unroll
        for (int f = 0; f < FW; ++f){
          acc[0][f] = __builtin_amdgcn_mfma_f32_16x16x32_bf16(ah0, bh[f], acc[0][f], 0,0,0);
          acc[0][f] = __builtin_amdgcn_mfma_f32_16x16x32_bf16(ah0, bl[f], acc[0][f], 0,0,0);
          acc[0][f] = __builtin_amdgcn_mfma_f32_16x16x32_bf16(al0, bh[f], acc[0][f], 0,0,0);
          acc[1][f] = __builtin_amdgcn_mfma_f32_16x16x32_bf16(ah1, bh[f], acc[1][f], 0,0,0);
          acc[1][f] = __builtin_amdgcn_mfma_f32_16x16x32_bf16(ah1, bl[f], acc[1][f], 0,0,0);
          acc[1][f] = __builtin_amdgcn_mfma_f32_16x16x32_bf16(al1, bh[f], acc[1][f], 0,0,0);
        }
      }
    }
  }

  const int orow = oh0 + rsel;
  if (orow >= 27) return;
  #pragma unroll
  for (int f = 0; f < FW; ++f){
    const int oc = (ocq*FW + f)*16 + c0;
    const float bv = bias[oc];
    #pragma unroll
    for (int m = 0; m < 2; ++m){
      #pragma unroll
      for (int r = 0; r < 4; ++r){
        const int ow = m*16 + (lane >> 4)*4 + r;
        if (ow >= 27) continue;
        float v = leakyf(acc[m][f][r] + bv);
        if (OUTM == 0){
          size_t o = (((size_t)n*29 + orow+1)*29 + ow+1)*OC + oc;
          unsigned short h = f2bf(v);
          OutHi[o] = h;
          OutLo[o] = f2bf(v - bf2f(h));
        } else {
          OutF[(((size_t)n*27 + orow)*27 + ow)*OC + oc] = v;
        }
      }
    }
  }
}

// ---------------- split-bf16 MFMA GEMM for MoE head -------------------------
template<int KTOT,int ACT,int OUTM>
__global__ __launch_bounds__(256) void gemmM_k(
    const unsigned short* __restrict__ Ah, const unsigned short* __restrict__ Al,
    long strideA,
    const unsigned short* __restrict__ Wh, const unsigned short* __restrict__ Wl,
    const float* __restrict__ bias, int N,
    unsigned short* __restrict__ OutH, unsigned short* __restrict__ OutL,
    float* __restrict__ OutF){
  const int e = blockIdx.z;
  Ah += (size_t)e * strideA; Al += (size_t)e * strideA;
  const int NF = N >> 4, KT = KTOT >> 5;
  const size_t wb = (size_t)e * NF * KT * 512;
  Wh += wb; Wl += wb;
  const float* bs = bias + (size_t)e * N;
  const size_t ob = (size_t)e * 256 * N;

  const int tid = threadIdx.x, wid = tid >> 6, lane = tid & 63;
  const int mblk = blockIdx.x * 32;
  const int nf = blockIdx.y * 4 + wid;
  const int r0 = mblk + (lane & 15);
  const int kof = (lane >> 4) * 8;

  f32x4 acc0 = {0,0,0,0}, acc1 = {0,0,0,0};
  for (int t = 0; t < KT; ++t){
    const int k = t*32 + kof;
    bf16x8 ah0 = *(const bf16x8*)(Ah + (size_t)r0*KTOT + k);
    bf16x8 al0 = *(const bf16x8*)(Al + (size_t)r0*KTOT + k);
    bf16x8 ah1 = *(const bf16x8*)(Ah + (size_t)(r0+16)*KTOT + k);
    bf16x8 al1 = *(const bf16x8*)(Al + (size_t)(r0+16)*KTOT + k);
    const size_t fb = ((size_t)t*NF + nf)*512 + lane*8;
    bf16x8 bh = *(const bf16x8*)(Wh + fb);
    bf16x8 bl = *(const bf16x8*)(Wl + fb);
    acc0 = __builtin_amdgcn_mfma_f32_16x16x32_bf16(ah0, bh, acc0, 0,0,0);
    acc0 = __builtin_amdgcn_mfma_f32_16x16x32_bf16(ah0, bl, acc0, 0,0,0);
    acc0 = __builtin_amdgcn_mfma_f32_16x16x32_bf16(al0, bh, acc0, 0,0,0);
    acc1 = __builtin_amdgcn_mfma_f32_16x16x32_bf16(ah1, bh, acc1, 0,0,0);
    acc1 = __builtin_amdgcn_mfma_f32_16x16x32_bf16(ah1, bl, acc1, 0,0,0);
    acc1 = __builtin_amdgcn_mfma_f32_16x16x32_bf16(al1, bh, acc1, 0,0,0);
  }
  const int n = nf*16 + (lane & 15);
  const float bv = bs[n];
  #pragma unroll
  for (int mi = 0; mi < 2; ++mi){
    f32x4 a = mi ? acc1 : acc0;
    #pragma unroll
    for (int r = 0; r < 4; ++r){
      const int m = mblk + mi*16 + (lane >> 4)*4 + r;
      float v = a[r] + bv;
      if (ACT == 1) v = leakyf(v);
      const size_t o = ob + (size_t)m*N + n;
      if (OUTM == 0){
        unsigned short h = f2bf(v);
        OutH[o] = h; OutL[o] = f2bf(v - bf2f(h));
      } else {
        OutF[o] = v;
      }
    }
  }
}

// ---------------- 2x2 stride-1 maxpool (NCHW) ----------------
template<int C,int IH,int IW>
__global__ __launch_bounds__(256) void pool_k(const float* __restrict__ in,
                                              float* __restrict__ out){
  constexpr int OH = IH - 1, OW = IW - 1;
  int idx = blockIdx.x * 256 + threadIdx.x;
  if (idx >= BATCH * C * OH * OW) return;
  int ow = idx % OW; int t = idx / OW;
  int oh = t % OH;   t /= OH;
  const float* p = in + ((size_t)t * IH + oh) * IW + ow;
  out[idx] = fmaxf(fmaxf(p[0], p[1]), fmaxf(p[IW], p[IW + 1]));
}

// ------- pool2: NHWC fp32 [B,28,28,32] -> padded NHWC bf16 hi/lo [B,29,29,32]
__global__ __launch_bounds__(256) void pool2n_k(const float* __restrict__ in,
    unsigned short* __restrict__ hi, unsigned short* __restrict__ lo){
  int idx = blockIdx.x*256 + threadIdx.x;
  if (idx >= BATCH*27*27*32) return;
  int ic = idx & 31; int p = idx >> 5;
  int ow = p % 27; int t = p / 27; int oh = t % 27; int n = t / 27;
  const float* b = in + (((size_t)n*28 + oh)*28 + ow)*32 + ic;
  float v = fmaxf(fmaxf(b[0], b[32]), fmaxf(b[28*32], b[29*32]));
  size_t o = (((size_t)n*29 + oh+1)*29 + ow+1)*32 + ic;
  unsigned short h = f2bf(v);
  hi[o] = h; lo[o] = f2bf(v - bf2f(h));
}

// ---------------- scout gate (NHWC input [B,28,28,32]) ----------------
__global__ __launch_bounds__(256) void gate_k(const float* __restrict__ s2,
                                              const float* __restrict__ cw,
                                              const float* __restrict__ cb,
                                              float* __restrict__ comb){
  int n = blockIdx.x;
  int tid = threadIdx.x;
  int c = tid & 31;
  int sub = tid >> 5;
  const float* p = s2 + (size_t)n * 784 * 32 + c;
  float s = 0.f;
  for (int i = sub * 98; i < sub * 98 + 98; ++i) s += p[(size_t)i * 32];
  __shared__ float red[32][8];
  red[c][sub] = s;
  __syncthreads();
  if (tid < 32){
    float tot = 0.f;
    #pragma unroll
    for (int k = 0; k < 8; ++k) tot += red[tid][k];
    red[tid][0] = tot / 784.f;
  }
  __syncthreads();
  if (tid == 0){
    float lg[3];
    for (int e = 0; e < 3; ++e){
      float a = cb[e];
      for (int c2 = 0; c2 < 32; ++c2) a += red[c2][0] * cw[e * 32 + c2];
      lg[e] = a;
    }
    float m = fmaxf(lg[0], fmaxf(lg[1], lg[2]));
    float ex[3], sum = 0.f;
    for (int e = 0; e < 3; ++e){ ex[e] = expf(lg[e] - m); sum += ex[e]; }
    float pr[3];
    for (int e = 0; e < 3; ++e) pr[e] = ex[e] / sum;
    int i1 = 0;
    if (pr[1] > pr[0]) i1 = 1;
    if (pr[2] > pr[i1]) i1 = 2;
    int i2 = -1;
    for (int e = 0; e < 3; ++e){
      if (e == i1) continue;
      if (i2 < 0 || pr[e] > pr[i2]) i2 = e;
    }
    float s12 = pr[i1] + pr[i2] + 1e-6f;
    float cmb[3] = {0.f, 0.f, 0.f};
    cmb[i1] = pr[i1] / s12;
    cmb[i2] = pr[i2] / s12;
    comb[n * 3 + 0] = cmb[0];
    comb[n * 3 + 1] = cmb[1];
    comb[n * 3 + 2] = cmb[2];
  }
}

// ------ fused maxpool2s1(27->26) + adaptive avg(26->3), NHWC input ----------
__global__ __launch_bounds__(256) void papooln_k(const float* __restrict__ in,
                                                 float* __restrict__ flat){
  int idx = blockIdx.x * 256 + threadIdx.x;
  if (idx >= BATCH * 128 * 9) return;
  int j = idx % 3; int t = idx / 3;
  int i = t % 3;   t /= 3;
  int c = t % 128; int n = t / 128;
  int hs = (i * 26) / 3, he = ((i + 1) * 26 + 2) / 3;
  int ws = (j * 26) / 3, we = ((j + 1) * 26 + 2) / 3;
  const float* p = in + (size_t)n * 729 * 128 + c;
  float s = 0.f;
  for (int r = hs; r < he; ++r)
    for (int cc = ws; cc < we; ++cc){
      const float* q0 = p + (r * 27 + cc) * 128;
      const float* q1 = q0 + 27 * 128;
      float m = fmaxf(fmaxf(q0[0], q0[128]), fmaxf(q1[0], q1[128]));
      s += m;
    }
  flat[(size_t)n * 1152 + c * 9 + i * 3 + j] = s / (float)((he - hs) * (we - ws));
}

// ---------------- final gated combine ----------------
__global__ __launch_bounds__(256) void comb_k(const float* __restrict__ h3,
                                              const float* __restrict__ comb,
                                              float* __restrict__ out){
  int idx = blockIdx.x * 256 + threadIdx.x;
  if (idx >= BATCH * 512) return;
  int o = idx % 512, b = idx / 512;
  float s = 0.f;
  #pragma unroll
  for (int e = 0; e < 3; ++e)
    s += comb[b * 3 + e] * h3[((size_t)e * BATCH + b) * 512 + o];
  out[idx] = s;
}

// ============================================================================
extern "C" void kernel_launch(void* const* d_in, const int* in_sizes, int n_in,
                              void* d_out, int out_size, void* d_ws, size_t ws_size,
                              hipStream_t stream){
  const float* x    = (const float*)d_in[0];
  const float* tw1  = (const float*)d_in[1];  const float* tb1 = (const float*)d_in[2];
  const float* tw2  = (const float*)d_in[3];  const float* tb2 = (const float*)d_in[4];
  const float* tw3  = (const float*)d_in[5];  const float* tb3 = (const float*)d_in[6];
  const float* tw4  = (const float*)d_in[7];  const float* tb4 = (const float*)d_in[8];
  const float* sw1  = (const float*)d_in[9];  const float* sb1 = (const float*)d_in[10];
  const float* bn1g = (const float*)d_in[11]; const float* bn1b = (const float*)d_in[12];
  const float* bn1m = (const float*)d_in[13]; const float* bn1v = (const float*)d_in[14];
  const float* sw2  = (const float*)d_in[15]; const float* sb2 = (const float*)d_in[16];
  const float* bn2g = (const float*)d_in[17]; const float* bn2b = (const float*)d_in[18];
  const float* bn2m = (const float*)d_in[19]; const float* bn2v = (const float*)d_in[20];
  const float* cw   = (const float*)d_in[21]; const float* cb  = (const float*)d_in[22];
  const float* ew1  = (const float*)d_in[23]; const float* eb1 = (const float*)d_in[24];
  const float* ew2  = (const float*)d_in[25]; const float* eb2 = (const float*)d_in[26];
  const float* ew3  = (const float*)d_in[27]; const float* eb3 = (const float*)d_in[28];
  float* out = (float*)d_out;

  // ---- workspace layout (floats), ~157 MB ----
  float* ws = (float*)d_ws;
  size_t off = 0;
  float* comb   = ws + off; off += 768;
  float* flat   = ws + off; off += (size_t)BATCH * 1152;
  float* h3     = ws + off; off += (size_t)BATCH * 3 * 512;
  unsigned short* wpk3h = (unsigned short*)(ws + off); off += 9216;
  unsigned short* wpk3l = (unsigned short*)(ws + off); off += 9216;
  unsigned short* wpk4h = (unsigned short*)(ws + off); off += 36864;
  unsigned short* wpk4l = (unsigned short*)(ws + off); off += 36864;
  unsigned short* wp2h  = (unsigned short*)(ws + off); off += 7680;
  unsigned short* wp2l  = (unsigned short*)(ws + off); off += 7680;
  unsigned short* wps2h = (unsigned short*)(ws + off); off += 3072;
  unsigned short* wps2l = (unsigned short*)(ws + off); off += 3072;
  unsigned short* wpfh  = (unsigned short*)(ws + off); off += 3072;  // 6144 ushort
  unsigned short* wpfl  = (unsigned short*)(ws + off); off += 3072;
  off += 16;                                                      // guard pad
  float* bufA   = ws + off; off += 13778944;
  off += 16;                                                      // guard pad
  float* bufB   = ws + off; off += 23887872;
  off += 16;
  (void)ws_size; (void)in_sizes; (void)n_in; (void)out_size;

  // phase aliases (lifetimes disjoint, single-stream ordered)
  float* s1out = bufA;                       // [B,16,56,56] NCHW
  float* c1out = bufB;                       // [B,16,56,56] NCHW
  float* s2out = bufB + 16000000;            // [B,28,28,32] NHWC
  float* p1out = bufA;                       // [B,16,55,55] NCHW
  float* c2out = bufB;                       // [B,28,28,32] NHWC
  unsigned short* P2h = (unsigned short*)(bufB + 8000000);
  unsigned short* P2l = P2h + (size_t)6889472;
  unsigned short* C3h = (unsigned short*)bufA;
  unsigned short* C3l = C3h + (size_t)13778944;
  float* c4out = bufB;                       // [B,27,27,128] NHWC

  // head-phase aliases in bufB (valid after papooln_k)
  unsigned short* ub = (unsigned short*)bufB;
  size_t uo = 0;
  unsigned short* ewp1h = ub + uo; uo += 3538944;
  unsigned short* ewp1l = ub + uo; uo += 3538944;
  unsigned short* ewp2h = ub + uo; uo += 1572864;
  unsigned short* ewp2l = ub + uo; uo += 1572864;
  unsigned short* ewp3h = ub + uo; uo += 786432;
  unsigned short* ewp3l = ub + uo; uo += 786432;
  unsigned short* fh    = ub + uo; uo += 294912;
  unsigned short* fl    = ub + uo; uo += 294912;
  unsigned short* h1h   = ub + uo; uo += 786432;
  unsigned short* h1l   = ub + uo; uo += 786432;
  unsigned short* h2h   = ub + uo; uo += 393216;
  unsigned short* h2l   = ub + uo; uo += 393216;

  dim3 blk(256);

  // ---- weight prep ----
  wpack_k<32,64>  <<<dim3(72),  blk, 0, stream>>>(tw3, wpk3h, wpk3l);
  wpack_k<64,128> <<<dim3(288), blk, 0, stream>>>(tw4, wpk4h, wpk4l);
  wpackS_k<32,5><<<dim3(60), blk, 0, stream>>>(tw2, wp2h, wp2l);
  wpackS_k<32,3><<<dim3(24), blk, 0, stream>>>(sw2, wps2h, wps2l);
  wpackF_k<<<dim3(24), blk, 0, stream>>>(sw1, tw1, wpfh, wpfl);

  // ---- fused scout1 + conv1 (space-to-depth MFMA, one pass over x) ----
  fusedM_k<<<dim3(BATCH*28), blk, 0, stream>>>(
      x, wpfh, wpfl, sb1, tb1, bn1g, bn1b, bn1m, bn1v, s1out, c1out);

  // ---- scout2 (MFMA strided) + gate ----
  convS_k<32,3,1,56,56,1><<<dim3(BATCH*28), blk, 0, stream>>>(
      s1out, wps2h, wps2l, sb2, bn2g, bn2b, bn2m, bn2v, s2out);
  gate_k<<<dim3(256), blk, 0, stream>>>(s2out, cw, cb, comb);

  // ---- pool1 -> conv2 (MFMA strided) ----
  pool_k<16,56,56><<<dim3(48400), blk, 0, stream>>>(c1out, p1out);
  convS_k<32,5,2,55,55,0><<<dim3(BATCH*28), blk, 0, stream>>>(
      p1out, wp2h, wp2l, tb2, nullptr, nullptr, nullptr, nullptr, c2out);

  // ---- pool2 -> padded NHWC bf16 hi/lo ----
  hipMemsetAsync(bufB + 8000000, 0, (size_t)2 * 6889472 * 2, stream);
  pool2n_k<<<dim3((BATCH*27*27*32 + 255)/256), blk, 0, stream>>>(c2out, P2h, P2l);

  // ---- conv3 (MFMA) -> padded NHWC bf16 hi/lo ----
  hipMemsetAsync(bufA, 0, (size_t)2 * 13778944 * 2, stream);
  convM_k<32,64,0><<<dim3(BATCH*14), blk, 0, stream>>>(
      P2h, P2l, wpk3h, wpk3l, tb3, C3h, C3l, nullptr);

  // ---- conv4 (MFMA) -> fp32 NHWC [B,27,27,128] ----
  convM_k<64,128,1><<<dim3(BATCH*14), blk, 0, stream>>>(
      C3h, C3l, wpk4h, wpk4l, tb4, nullptr, nullptr, c4out);

  papooln_k<<<dim3(1152), blk, 0, stream>>>(c4out, flat);

  // ---- MoE head: pack weights + split A, then 3 MFMA GEMMs ----
  wpackG_k<1152><<<dim3(4608,3), blk, 0, stream>>>(ew1, 1024, ewp1h, ewp1l);
  wpackG_k<1024><<<dim3(2048,3), blk, 0, stream>>>(ew2,  512, ewp2h, ewp2l);
  wpackG_k< 512><<<dim3(1024,3), blk, 0, stream>>>(ew3,  512, ewp3h, ewp3l);
  asplit_k<<<dim3(1152), blk, 0, stream>>>(flat, fh, fl, BATCH*1152);

  gemmM_k<1152,1,0><<<dim3(8,16,3), blk, 0, stream>>>(
      fh, fl, 0L, ewp1h, ewp1l, eb1, 1024, h1h, h1l, nullptr);
  gemmM_k<1024,1,0><<<dim3(8,8,3), blk, 0, stream>>>(
      h1h, h1l, 256L*1024, ewp2h, ewp2l, eb2, 512, h2h, h2l, nullptr);
  gemmM_k< 512,0,1><<<dim3(8,8,3), blk, 0, stream>>>(
      h2h, h2l, 256L*512, ewp3h, ewp3l, eb3, 512, nullptr, nullptr, h3);

  comb_k<<<dim3(512), blk, 0, stream>>>(h3, comb, out);
}